// Round 14
// baseline (1059.581 us; speedup 1.0000x reference)
//
#include <hip/hip_runtime.h>
#include <math.h>

#define HW 9216
#define WIDTH 96
#define FSTRIDE (512*HW)          // 4718592
#define RSTRIDE (256*HW)          // 2359296
#define TABSTRIDE (9*HW)          // 82944
#define PXP 12544                 // 98 rows * 128
#define FTPROWS 12800             // 100 rows (guard + 98 + guard)

typedef __attribute__((ext_vector_type(8))) short bf16x8;
typedef __attribute__((ext_vector_type(4))) float f32x4;
typedef __attribute__((ext_vector_type(8))) unsigned short u16x8;

__device__ __forceinline__ unsigned short f2bf(float f) {
  unsigned int u = __float_as_uint(f);
  u += 0x7FFFu + ((u >> 16) & 1u);   // RNE
  return (unsigned short)(u >> 16);
}
__device__ __forceinline__ float bf2f(unsigned short s) {
  return __uint_as_float(((unsigned int)s) << 16);
}

#define GLDS(g, l) __builtin_amdgcn_global_load_lds( \
    (const __attribute__((address_space(1))) unsigned int*)(g), \
    (__attribute__((address_space(3))) unsigned int*)(l), 16, 0, 0)

// ---------------- zero helper ----------------
__global__ void k_zero(unsigned short* p, unsigned int n8) {
  unsigned int i = blockIdx.x * 256 + threadIdx.x;
  if (i < n8) ((u16x8*)p)[i] = (u16x8){0, 0, 0, 0, 0, 0, 0, 0};
}

// ---------------- ftp from concat sources: [b][pxp][C] bf16 ----------------
__global__ void __launch_bounds__(256) k_mkftp_cat(
    const float* __restrict__ lo0, const float* __restrict__ lo1,
    const float* __restrict__ hi, unsigned short* __restrict__ dst,
    int C, int CB) {
  const int b = blockIdx.z;
  const float* lo = b ? lo1 : lo0;
  unsigned short* d = dst + (size_t)b * FTPROWS * C + 128 * C;
  const int px0 = blockIdx.x * 64, c0 = blockIdx.y * 64;
  __shared__ float tile[64][65];
  const int t = threadIdx.x;
#pragma unroll
  for (int rep = 0; rep < 16; ++rep) {
    int idx = rep * 256 + t;
    int cl = idx >> 6, pl = idx & 63;
    int cg = c0 + cl;
    const float* s = (cg < CB) ? (lo + (size_t)cg * HW) : (hi + (size_t)(cg - CB) * HW);
    tile[cl][pl] = s[px0 + pl];
  }
  __syncthreads();
  const int pl = t >> 2, cu = (t & 3) * 16;
  const int px = px0 + pl;
  const int h = px / WIDTH, w = px - h * WIDTH;
  const size_t pxp = (size_t)(h + 1) * 128 + (w + 1);
  u16x8 o0, o1;
#pragma unroll
  for (int j = 0; j < 8; ++j) o0[j] = f2bf(tile[cu + j][pl]);
#pragma unroll
  for (int j = 0; j < 8; ++j) o1[j] = f2bf(tile[cu + 8 + j][pl]);
  unsigned short* p = d + pxp * C + c0 + cu;
  *(u16x8*)p = o0;
  *(u16x8*)(p + 8) = o1;
}

// ---------------- ftp from GN(yh bf16)+ReLU (C=512, CperG=16) --------------
__global__ void __launch_bounds__(256) k_mkftp_gn(
    const unsigned short* __restrict__ yh, const float2* __restrict__ stat,
    const float* __restrict__ gamma, const float* __restrict__ beta,
    unsigned short* __restrict__ dst) {
  const int C = 512;
  const int b = blockIdx.z;
  unsigned short* d = dst + (size_t)b * FTPROWS * C + 128 * C;
  const int px0 = blockIdx.x * 64, c0 = blockIdx.y * 64;
  __shared__ float tile[64][65];
  const int t = threadIdx.x;
#pragma unroll
  for (int rep = 0; rep < 16; ++rep) {
    int idx = rep * 256 + t;
    int cl = idx >> 6, pl = idx & 63;
    int cg = c0 + cl;
    float2 st = stat[b * 32 + (cg >> 4)];
    float v = bf2f(yh[(size_t)b * FSTRIDE + (size_t)cg * HW + px0 + pl]);
    v = (v - st.x) * st.y * gamma[cg] + beta[cg];
    tile[cl][pl] = fmaxf(v, 0.f);
  }
  __syncthreads();
  const int pl = t >> 2, cu = (t & 3) * 16;
  const int px = px0 + pl;
  const int h = px / WIDTH, w = px - h * WIDTH;
  const size_t pxp = (size_t)(h + 1) * 128 + (w + 1);
  u16x8 o0, o1;
#pragma unroll
  for (int j = 0; j < 8; ++j) o0[j] = f2bf(tile[cu + j][pl]);
#pragma unroll
  for (int j = 0; j < 8; ++j) o1[j] = f2bf(tile[cu + 8 + j][pl]);
  unsigned short* p = d + pxp * C + c0 + cu;
  *(u16x8*)p = o0;
  *(u16x8*)(p + 8) = o1;
}

// ------- offconv weights, ALL layers: Wt[lyr][k][oc(32 pad)][c] bf16 -------
__global__ void k_prepW_all(const float* __restrict__ ow0, const float* __restrict__ ow1,
                            const float* __restrict__ ow2, const float* __restrict__ ow3,
                            unsigned short* __restrict__ wt) {
  int i = blockIdx.x * 256 + threadIdx.x;      // < 4*9*32*512
  int lyr = i / 147456, r0 = i % 147456;
  const float* ow = (lyr == 0) ? ow0 : (lyr == 1) ? ow1 : (lyr == 2) ? ow2 : ow3;
  int k = r0 / (32 * 512), r = r0 - k * 32 * 512;
  int oc = r / 512, c = r - oc * 512;
  wt[i] = (oc < 18) ? f2bf(ow[((size_t)oc * 512 + c) * 9 + k]) : (unsigned short)0;
}

// ------- dcgemm weights, ALL layers: Ap[m][k*C+c] = dw[m][c][k] bf16 -------
// layers 0-2: 512*4608 elems at lyr*2359296; layer 3: 256*2304 at 7077888.
__global__ void k_prepA_all(const float* __restrict__ dw0, const float* __restrict__ dw1,
                            const float* __restrict__ dw2, const float* __restrict__ dw3,
                            unsigned short* __restrict__ ap) {
  int i = blockIdx.x * 256 + threadIdx.x;      // < 7667712
  int lyr, o, C; size_t base;
  if (i < 7077888) { lyr = i / 2359296; o = i % 2359296; C = 512; base = (size_t)lyr * 2359296; }
  else             { lyr = 3; o = i - 7077888; C = 256; base = 7077888; }
  const float* dw = (lyr == 0) ? dw0 : (lyr == 1) ? dw1 : (lyr == 2) ? dw2 : dw3;
  int K = 9 * C;
  int m = o / K, r = o - m * K;
  int k = r / C, c = r - k * C;
  ap[base + o] = f2bf(dw[((size_t)m * C + c) * 9 + k]);
}

// ---------------- offset conv via MFMA, 2-deep pipeline ----------------
__global__ void __launch_bounds__(256) k_offmm(const unsigned short* __restrict__ ftp,
                                               const unsigned short* __restrict__ Wt,
                                               float* __restrict__ part) {
  const int C = 512;
  __shared__ unsigned short As[2][128 * 64];  // 2 x 16 KB
  __shared__ unsigned short Bs[2][32 * 64];   // 2 x 4 KB
  const int tid = threadIdx.x;
  const int lane = tid & 63, wv = tid >> 6;
  const int b = blockIdx.z, ks = blockIdx.y;
  const int pxp0 = 128 + blockIdx.x * 128;
  const unsigned short* fb = ftp + (size_t)b * FTPROWS * C + 128 * C;

  const int lr = lane >> 3;
  const int lu = lane & 7;
  const int fr = lane & 15, hi = lane >> 4;

  f32x4 acc[2][2];
#pragma unroll
  for (int i = 0; i < 2; ++i)
#pragma unroll
    for (int j = 0; j < 2; ++j) acc[i][j] = (f32x4){0.f, 0.f, 0.f, 0.f};

#define OFFMM_STAGE(S, BUF)                                                   \
  {                                                                           \
    const int k_ = ks * 3 + ((S) >> 3);                                       \
    const int dlt_ = (k_ / 3 - 1) * 128 + (k_ % 3 - 1);                       \
    const int c0_ = ((S) & 7) * 64;                                           \
    _Pragma("unroll")                                                         \
    for (int q = 0; q < 4; ++q) {                                             \
      int row = wv * 32 + q * 8 + lr;                                         \
      int su = lu ^ (row & 7);                                                \
      GLDS(fb + (size_t)(pxp0 + dlt_ + row) * C + c0_ + su * 8,               \
           (char*)&As[BUF][0] + (wv * 32 + q * 8) * 128);                     \
    }                                                                         \
    {                                                                         \
      int row = wv * 8 + lr;                                                  \
      int su = lu ^ (row & 7);                                                \
      GLDS(Wt + ((size_t)k_ * 32 + row) * C + c0_ + su * 8,                   \
           (char*)&Bs[BUF][0] + wv * 8 * 128);                                \
    }                                                                         \
  }

  OFFMM_STAGE(0, 0);
  for (int s = 0; s < 24; ++s) {
    const int cur = s & 1;
    if (s + 1 < 24) {
      OFFMM_STAGE(s + 1, cur ^ 1);
      asm volatile("s_waitcnt vmcnt(5)" ::: "memory");
    } else {
      asm volatile("s_waitcnt vmcnt(0)" ::: "memory");
    }
    __builtin_amdgcn_s_barrier();
#pragma unroll
    for (int kk = 0; kk < 2; ++kk) {
      bf16x8 a[2], bb[2];
#pragma unroll
      for (int i = 0; i < 2; ++i) {
        int row = wv * 32 + i * 16 + fr;
        a[i] = *(const bf16x8*)&As[cur][row * 64 + (((kk * 4 + hi) ^ (row & 7)) * 8)];
      }
#pragma unroll
      for (int j = 0; j < 2; ++j) {
        int row = j * 16 + fr;
        bb[j] = *(const bf16x8*)&Bs[cur][row * 64 + (((kk * 4 + hi) ^ (row & 7)) * 8)];
      }
#pragma unroll
      for (int i = 0; i < 2; ++i)
#pragma unroll
        for (int j = 0; j < 2; ++j)
          acc[i][j] = __builtin_amdgcn_mfma_f32_16x16x32_bf16(a[i], bb[j], acc[i][j], 0, 0, 0);
    }
    __builtin_amdgcn_s_barrier();
  }

  float* pb = part + ((size_t)(b * 3 + ks)) * PXP * 32;
#pragma unroll
  for (int i = 0; i < 2; ++i)
#pragma unroll
    for (int j = 0; j < 2; ++j) {
      int row0 = pxp0 + wv * 32 + i * 16 + hi * 4;
      int col = j * 16 + fr;
#pragma unroll
      for (int q = 0; q < 4; ++q)
        pb[(size_t)(row0 + q) * 32 + col] = acc[i][j][q];
    }
}

// ---------------- bilinear tables ----------------
__global__ void k_table(const float* __restrict__ part, const float* __restrict__ ob,
                        int4* __restrict__ tabi, float4* __restrict__ tabw) {
  int b = blockIdx.z, k = blockIdx.y;
  int px = blockIdx.x * 256 + threadIdx.x;
  int h = px / WIDTH, w = px - h * WIDTH;
  size_t pxp = (size_t)(h + 1) * 128 + (w + 1);
  const float* pb = part + (size_t)b * 3 * PXP * 32 + pxp * 32;
  float dy = ob[2 * k] + pb[2 * k] + pb[(size_t)PXP * 32 + 2 * k] + pb[2 * (size_t)PXP * 32 + 2 * k];
  float dx = ob[2 * k + 1] + pb[2 * k + 1] + pb[(size_t)PXP * 32 + 2 * k + 1] + pb[2 * (size_t)PXP * 32 + 2 * k + 1];
  float py = (float)(h - 1 + k / 3) + dy;
  float pxx = (float)(w - 1 + k % 3) + dx;
  float y0 = floorf(py), x0 = floorf(pxx);
  float ay = py - y0, ax = pxx - x0;
  float wy[2] = {1.f - ay, ay}, wx[2] = {1.f - ax, ax};
  int idx[4]; float wt[4];
#pragma unroll
  for (int t = 0; t < 4; ++t) {
    float oy = y0 + (float)(t >> 1);
    float ox = x0 + (float)(t & 1);
    bool valid = (oy >= 0.f) && (oy <= 95.f) && (ox >= 0.f) && (ox <= 95.f);
    int yi = (int)fminf(fmaxf(oy, 0.f), 95.f);
    int xi = (int)fminf(fmaxf(ox, 0.f), 95.f);
    idx[t] = (yi + 1) * 128 + (xi + 1);
    wt[t] = valid ? wy[t >> 1] * wx[t & 1] : 0.f;
  }
  size_t e = (size_t)b * TABSTRIDE + (size_t)k * HW + px;
  tabi[e] = make_int4(idx[0], idx[1], idx[2], idx[3]);
  tabw[e] = make_float4(wt[0], wt[1], wt[2], wt[3]);
}

// ------- sampled from ftp, 32 ch/thread, XCD-chunked 1D grid --------------
// nwg = 144 * yc * (2*nk), yc = C/128; logical l: c inner, px mid, (b,k) outer
__global__ void __launch_bounds__(256) k_sample2(
    const unsigned short* __restrict__ ftp,
    const int4* __restrict__ tabi, const float4* __restrict__ tabw,
    unsigned short* __restrict__ samp, int C, int kbase, int rowK, int yc) {
  const int nwg = gridDim.x;
  const int cpx = nwg >> 3;
  const int bid = blockIdx.x;
  const int l = (bid & 7) * cpx + (bid >> 3);
  const int ci = l % yc;
  const int r = l / yc;
  const int pxi = r % 144;
  const int zk = r / 144;
  const int b = zk & 1, kloc = zk >> 1;
  const int k = kbase + kloc;
  const int t = threadIdx.x;
  const int px = pxi * 64 + (t >> 2);
  const int c = ci * 128 + (t & 3) * 32;
  const unsigned short* fb = ftp + (size_t)b * FTPROWS * C + 128 * C;
  size_t e = (size_t)b * TABSTRIDE + (size_t)k * HW + px;
  int4 id = tabi[e];
  float4 wt = tabw[e];
  float acc[32];
#pragma unroll
  for (int j = 0; j < 32; ++j) acc[j] = 0.f;
  const int ids[4] = {id.x, id.y, id.z, id.w};
  const float wts[4] = {wt.x, wt.y, wt.z, wt.w};
#pragma unroll
  for (int s = 0; s < 4; ++s) {
    const unsigned short* p = fb + (size_t)ids[s] * C + c;
    float wgt = wts[s];
#pragma unroll
    for (int v = 0; v < 4; ++v) {
      u16x8 vv = *(const u16x8*)(p + v * 8);
#pragma unroll
      for (int j = 0; j < 8; ++j) acc[v * 8 + j] += wgt * bf2f(vv[j]);
    }
  }
  unsigned short* dst = samp + ((size_t)b * HW + px) * rowK + kloc * C + c;
#pragma unroll
  for (int v = 0; v < 4; ++v) {
    u16x8 o;
#pragma unroll
    for (int j = 0; j < 8; ++j) o[j] = f2bf(acc[v * 8 + j]);
    *(u16x8*)(dst + v * 8) = o;
  }
}

// ---- staging 128x96 BK=32: A=8 units, B=6 units; w0,w1:2A+2B; w2,w3:2A+1B --
__device__ __forceinline__ void stage_ab96(const unsigned short* __restrict__ Ag,
                                           const unsigned short* __restrict__ Bg,
                                           int lda, int rowK, int kt,
                                           unsigned short* as_, unsigned short* bs_,
                                           int wv, int lane) {
  const int lr = lane >> 2;
  const int lu = lane & 3;
#pragma unroll
  for (int q = 0; q < 2; ++q) {
    int row = wv * 32 + q * 16 + lr;
    int su = lu ^ ((row >> 1) & 3);
    GLDS(Ag + (size_t)row * lda + kt + su * 8, (char*)as_ + (wv * 2 + q) * 1024);
  }
  const int nb = (wv < 2) ? 2 : 1;
  const int bu0 = (wv < 2) ? (2 * wv) : (wv + 2);
  for (int q = 0; q < nb; ++q) {
    int unit = bu0 + q;
    int row = unit * 16 + lr;
    int su = lu ^ ((row >> 1) & 3);
    GLDS(Bg + (size_t)row * rowK + kt + su * 8, (char*)bs_ + unit * 1024);
  }
}

// ---------------- bf16 MFMA GEMM: 128m x 96n, BK=32, 3-stage, bf16 Y -------
// (R11/R13-verified: 4 waves of 64m x 48n, occupancy ~30%)
__global__ void __launch_bounds__(256) k_dcgemm(
    const unsigned short* __restrict__ Ap, const unsigned short* __restrict__ Bt,
    unsigned short* __restrict__ Yh, float2* __restrict__ gnp,
    int lda, int rowK, int aOff, int accum, int CperG, int dogn) {
  __shared__ unsigned short As[3][128 * 32];
  __shared__ unsigned short Bs[3][96 * 32];
  const int tid = threadIdx.x;
  const int lane = tid & 63, wv = tid >> 6;

  const int nwg = gridDim.x;
  const int cpx = nwg >> 3;
  const int bid = blockIdx.x;
  const int l = (bid & 7) * cpx + (bid >> 3);
  const int nm = nwg / 192;
  const int m_i = l % nm;
  const int rest = l / nm;
  const int n_i = rest % 96;
  const int b = rest / 96;

  const int m0 = m_i << 7, n0 = n_i * 96;
  const unsigned short* Ag = Ap + (size_t)m0 * lda + aOff;
  const unsigned short* Bg = Bt + ((size_t)b * HW + n0) * rowK;

  const int wm = (wv >> 1) * 64, wn = (wv & 1) * 48;
  const int fr = lane & 15, hi = lane >> 4;
  const int nt = rowK >> 5;

  f32x4 acc[4][3];
#pragma unroll
  for (int i = 0; i < 4; ++i)
#pragma unroll
    for (int j = 0; j < 3; ++j) acc[i][j] = (f32x4){0.f, 0.f, 0.f, 0.f};

  stage_ab96(Ag, Bg, lda, rowK, 0,  &As[0][0], &Bs[0][0], wv, lane);
  stage_ab96(Ag, Bg, lda, rowK, 32, &As[1][0], &Bs[1][0], wv, lane);

  for (int t = 0; t < nt; ++t) {
    const int cur = t % 3;
    if (t + 2 < nt) {
      stage_ab96(Ag, Bg, lda, rowK, (t + 2) << 5, &As[(t + 2) % 3][0],
                 &Bs[(t + 2) % 3][0], wv, lane);
      if (wv < 2) asm volatile("s_waitcnt vmcnt(8)" ::: "memory");
      else        asm volatile("s_waitcnt vmcnt(6)" ::: "memory");
    } else if (t + 1 < nt) {
      if (wv < 2) asm volatile("s_waitcnt vmcnt(4)" ::: "memory");
      else        asm volatile("s_waitcnt vmcnt(3)" ::: "memory");
    } else {
      asm volatile("s_waitcnt vmcnt(0)" ::: "memory");
    }
    __builtin_amdgcn_s_barrier();
    __builtin_amdgcn_sched_barrier(0);
    bf16x8 a[4], bb[3];
#pragma unroll
    for (int i = 0; i < 4; ++i) {
      int row = wm + i * 16 + fr;
      a[i] = *(const bf16x8*)&As[cur][row * 32 + ((hi ^ ((row >> 1) & 3)) * 8)];
    }
#pragma unroll
    for (int j = 0; j < 3; ++j) {
      int row = wn + j * 16 + fr;
      bb[j] = *(const bf16x8*)&Bs[cur][row * 32 + ((hi ^ ((row >> 1) & 3)) * 8)];
    }
    __builtin_amdgcn_s_setprio(1);
#pragma unroll
    for (int i = 0; i < 4; ++i)
#pragma unroll
      for (int j = 0; j < 3; ++j)
        acc[i][j] = __builtin_amdgcn_mfma_f32_16x16x32_bf16(a[i], bb[j], acc[i][j], 0, 0, 0);
    __builtin_amdgcn_s_setprio(0);
    __builtin_amdgcn_s_barrier();
  }

  unsigned short* Yb = Yh + (size_t)b * FSTRIDE;
  const int orow = m0 + wm + hi * 4;
  const int ocol = n0 + wn + fr;
  float s_[4], q_[4];
#pragma unroll
  for (int i = 0; i < 4; ++i) { s_[i] = 0.f; q_[i] = 0.f; }
#pragma unroll
  for (int i = 0; i < 4; ++i) {
#pragma unroll
    for (int j = 0; j < 3; ++j) {
      unsigned short* p = Yb + (size_t)(orow + i * 16) * HW + ocol + j * 16;
#pragma unroll
      for (int q = 0; q < 4; ++q) {
        float v = acc[i][j][q];
        if (accum) v += bf2f(p[(size_t)q * HW]);
        p[(size_t)q * HW] = f2bf(v);
        s_[i] += v;
        q_[i] += v * v;
      }
    }
  }

  if (dogn) {
    const int redmax = (CperG == 16) ? 32 : 16;
#pragma unroll
    for (int i = 0; i < 4; ++i) {
      float s = s_[i], q = q_[i];
      for (int off = 1; off <= redmax; off <<= 1) {
        s += __shfl_xor(s, off);
        q += __shfl_xor(q, off);
      }
      int row0 = m0 + wm + i * 16 + ((CperG == 8) ? (lane >> 5) * 8 : 0);
      int g = row0 / CperG;
      bool writer = (CperG == 16) ? (lane == 0) : ((lane & 31) == 0);
      if (writer)
        gnp[(((size_t)(b * 32 + g)) * 96 + n_i) * 2 + (wv & 1)] = make_float2(s, q);
    }
  }
}

// ---------------- GN finalize from dcgemm partials (192 slots/group) -------
__global__ void k_gnfin2(const float2* __restrict__ gnp, float2* __restrict__ stat,
                         int CperG) {
  int t = threadIdx.x;  // 0..63 = b*32+g
  float s = 0.f, q = 0.f;
  for (int j = 0; j < 192; ++j) {
    float2 v = gnp[(size_t)t * 192 + j];
    s += v.x; q += v.y;
  }
  float n = (float)(CperG * HW);
  float m = s / n;
  float var = q / n - m * m;
  stat[t] = make_float2(m, rsqrtf(var + 1e-5f));
}

// ---------------- fallback GN stats from yh (3-chunk path only) ------------
__global__ void __launch_bounds__(256) k_gnstats1h(const unsigned short* __restrict__ yh,
                                                   float2* __restrict__ part, int CperG) {
  const int b = blockIdx.z, g = blockIdx.x, ch = blockIdx.y;
  const int n = CperG * HW;
  const int cs8 = (n >> 4) >> 3;
  const u16x8* p = (const u16x8*)(yh + (size_t)b * FSTRIDE + (size_t)g * n + (size_t)ch * (n >> 4));
  float s = 0.f, q = 0.f;
  for (int i = threadIdx.x; i < cs8; i += 256) {
    u16x8 v = p[i];
#pragma unroll
    for (int j = 0; j < 8; ++j) { float f = bf2f(v[j]); s += f; q += f * f; }
  }
  __shared__ float ss[256], qs[256];
  ss[threadIdx.x] = s; qs[threadIdx.x] = q;
  __syncthreads();
  for (int d = 128; d > 0; d >>= 1) {
    if (threadIdx.x < d) { ss[threadIdx.x] += ss[threadIdx.x + d]; qs[threadIdx.x] += qs[threadIdx.x + d]; }
    __syncthreads();
  }
  if (threadIdx.x == 0) part[((b << 5) + g) * 16 + ch] = make_float2(ss[0], qs[0]);
}

__global__ void k_gnfin(const float2* __restrict__ part, float2* __restrict__ stat,
                        int CperG) {
  int t = threadIdx.x;
  float s = 0.f, q = 0.f;
#pragma unroll
  for (int j = 0; j < 16; ++j) { float2 v = part[t * 16 + j]; s += v.x; q += v.y; }
  float n = (float)(CperG * HW);
  float m = s / n;
  float var = q / n - m * m;
  stat[t] = make_float2(m, rsqrtf(var + 1e-5f));
}

// ------- fused layer-4 GN-apply + cosine partials ----------
__global__ void __launch_bounds__(256) k_gncos(
    const unsigned short* __restrict__ yh, const float2* __restrict__ stat,
    const float* __restrict__ gamma, const float* __restrict__ beta,
    float* __restrict__ res, float4* __restrict__ cospart) {
  int px = blockIdx.x * 256 + threadIdx.x;
  int cc = blockIdx.y;
  float saa = 0.f, sbb = 0.f, sab = 0.f;
  for (int c = cc * 32; c < cc * 32 + 32; ++c) {
    float2 st0 = stat[c >> 3];
    float2 st1 = stat[32 + (c >> 3)];
    float ga = gamma[c], be = beta[c];
    float a = fmaxf((bf2f(yh[(size_t)c * HW + px]) - st0.x) * st0.y * ga + be, 0.f);
    float b = fmaxf((bf2f(yh[(size_t)FSTRIDE + (size_t)c * HW + px]) - st1.x) * st1.y * ga + be, 0.f);
    res[(size_t)c * HW + px] = a;
    res[(size_t)RSTRIDE + (size_t)c * HW + px] = b;
    saa += a * a; sbb += b * b; sab += a * b;
  }
  cospart[(size_t)cc * HW + px] = make_float4(saa, sbb, sab, 0.f);
}

__global__ void k_cos2(const float4* __restrict__ part, float* __restrict__ wpix) {
  int px = blockIdx.x * 256 + threadIdx.x;
  float saa = 0.f, sbb = 0.f, sab = 0.f;
#pragma unroll
  for (int cc = 0; cc < 8; ++cc) {
    float4 v = part[(size_t)cc * HW + px];
    saa += v.x; sbb += v.y; sab += v.z;
  }
  float na = sqrtf(saa), nb = sqrtf(sbb);
  float ttw = saa / fmaxf(na * na, 1e-8f);
  float tkw = sab / fmaxf(na * nb, 1e-8f);
  float m = fmaxf(ttw, tkw);
  float e0 = expf(ttw - m), e1 = expf(tkw - m);
  wpix[px] = e0 / (e0 + e1);
}

__global__ void k_combine(const float* __restrict__ res, const float* __restrict__ wpix,
                          float* __restrict__ out) {
  int i = blockIdx.x * 256 + threadIdx.x;
  int px = i % HW;
  float w0 = wpix[px];
  out[i] = w0 * res[i] + (1.f - w0) * res[(size_t)RSTRIDE + i];
}

extern "C" void kernel_launch(void* const* d_in, const int* in_sizes, int n_in,
                              void* d_out, int out_size, void* d_ws, size_t ws_size,
                              hipStream_t stream) {
  const float* datas = (const float*)d_in[0];
  const float* ow[4] = {(const float*)d_in[1], (const float*)d_in[6],
                        (const float*)d_in[11], (const float*)d_in[16]};
  const float* ob[4] = {(const float*)d_in[2], (const float*)d_in[7],
                        (const float*)d_in[12], (const float*)d_in[17]};
  const float* dw[4] = {(const float*)d_in[3], (const float*)d_in[8],
                        (const float*)d_in[13], (const float*)d_in[18]};
  const float* gg[4] = {(const float*)d_in[4], (const float*)d_in[9],
                        (const float*)d_in[14], (const float*)d_in[19]};
  const float* gb[4] = {(const float*)d_in[5], (const float*)d_in[10],
                        (const float*)d_in[15], (const float*)d_in[20]};

  // full-K layout needs ~247.8 MB (all-layer Ap/Wt hoisted); R6 proved
  // ws_size >= 255.1 MB on this harness, so gate at the layout size.
  const int fullk = (ws_size >= 248500000ull) ? 1 : 0;
  const size_t sampN = fullk ? (2 * (size_t)HW * 4608) : (2 * (size_t)HW * 1536);

  float* ws = (float*)d_ws;
  unsigned short* yh = (unsigned short*)ws;               // 2*FSTRIDE bf16
  float* offp3 = ws + (2 * (size_t)FSTRIDE * 2) / 4;      // 2*3*PXP*32 fp32
  float4* tabw = (float4*)(offp3 + 2 * 3 * (size_t)PXP * 32);
  int4*   tabi = (int4*)(tabw + 2 * (size_t)TABSTRIDE);
  float* wpix = (float*)(tabi + 2 * (size_t)TABSTRIDE);   // HW
  float2* stat = (float2*)(wpix + HW);                    // 64
  float2* gnp  = stat + 64;                               // 2*32*96*2 float2
  float2* gnpart = gnp + 2 * 32 * 96 * 2;                 // 1024 (fallback)
  float4* cospart = (float4*)(gnpart + 1024);             // 8*HW
  float* endp = (float*)(cospart + 8 * (size_t)HW);
  size_t ofs = ((size_t)(endp - ws) + 3) & ~(size_t)3;
  unsigned short* samp = (unsigned short*)(ws + ofs);
  unsigned short* apAll = samp + sampN;                   // 7667712 us (15.3MB)
  unsigned short* wtAll = apAll + (size_t)7667712;        // 589824 us (1.2MB)
  unsigned short* ftp512 = wtAll + (size_t)589824;        // 2*FTPROWS*512
  unsigned short* ftp256 = fullk ? (samp + 2 * (size_t)HW * 2304)
                                 : (ftp512 + 2 * (size_t)FTPROWS * 512);
  float* res = (float*)(ftp256 + 2 * (size_t)FTPROWS * 256);

  dim3 blk(256);
  k_zero<<<dim3(2 * FTPROWS * 512 / 8 / 256), blk, 0, stream>>>(ftp512, 2u * FTPROWS * 512 / 8);
  k_prepA_all<<<dim3(29952), blk, 0, stream>>>(dw[0], dw[1], dw[2], dw[3], apAll);
  k_prepW_all<<<dim3(2304), blk, 0, stream>>>(ow[0], ow[1], ow[2], ow[3], wtAll);

  for (int lyr = 0; lyr < 4; ++lyr) {
    const int Cx = (lyr < 3) ? 512 : 256;
    const int M  = Cx;
    const int CperG = (lyr < 3) ? 16 : 8;
    const unsigned short* Ap = (lyr < 3) ? (apAll + (size_t)lyr * 2359296)
                                         : (apAll + (size_t)7077888);
    const unsigned short* Wt = wtAll + (size_t)lyr * 147456;
    if (lyr == 0) {
      k_mkftp_cat<<<dim3(144, 8, 2), blk, 0, stream>>>(datas + RSTRIDE, datas,
                                                       datas + RSTRIDE, ftp512, 512, 256);
    } else {
      k_mkftp_gn<<<dim3(144, 8, 2), blk, 0, stream>>>(yh, stat, gg[lyr - 1], gb[lyr - 1],
                                                      ftp512);
    }
    k_offmm<<<dim3(96, 3, 2), blk, 0, stream>>>(ftp512, Wt, offp3);
    k_table<<<dim3(36, 9, 2), blk, 0, stream>>>(offp3, ob[lyr], tabi, tabw);
    const unsigned short* sftp;
    if (lyr < 3) {
      sftp = ftp512;
    } else {
      k_zero<<<dim3(2 * FTPROWS * 256 / 8 / 256), blk, 0, stream>>>(ftp256, 2u * FTPROWS * 256 / 8);
      k_mkftp_cat<<<dim3(144, 4, 2), blk, 0, stream>>>(datas + RSTRIDE, datas,
                                                       datas, ftp256, 256, 256);
      sftp = ftp256;
    }
    const int nch = fullk ? 1 : 3;
    const int nk = 9 / nch;
    const int rowK = nk * Cx;
    const int yc = Cx / 128;
    for (int ch = 0; ch < nch; ++ch) {
      k_sample2<<<dim3(144 * yc * 2 * nk), blk, 0, stream>>>(sftp, tabi, tabw, samp,
                                                             Cx, ch * nk, rowK, yc);
      k_dcgemm<<<dim3((M / 128) * 96 * 2), blk, 0, stream>>>(
          Ap, samp, yh, gnp, 9 * Cx, rowK, ch * rowK, ch > 0, CperG,
          fullk && (ch == nch - 1));
    }
    if (fullk) {
      k_gnfin2<<<dim3(1), dim3(64), 0, stream>>>(gnp, stat, CperG);
    } else {
      k_gnstats1h<<<dim3(32, 16, 2), blk, 0, stream>>>(yh, gnpart, CperG);
      k_gnfin<<<dim3(1), dim3(64), 0, stream>>>(gnpart, stat, CperG);
    }
  }

  // layer-4 fused GN-apply + cosine partials, then blend
  k_gncos<<<dim3(36, 8), blk, 0, stream>>>(yh, stat, gg[3], gb[3], res, cospart);
  k_cos2<<<dim3(36), blk, 0, stream>>>(cospart, wpix);
  k_combine<<<dim3(RSTRIDE / 256), blk, 0, stream>>>(res, wpix, (float*)d_out);
}

// Round 15
// 971.355 us; speedup vs baseline: 1.0908x; 1.0908x over previous
//
#include <hip/hip_runtime.h>
#include <math.h>

#define HW 9216
#define WIDTH 96
#define FSTRIDE (512*HW)          // 4718592
#define RSTRIDE (256*HW)          // 2359296
#define TABSTRIDE (9*HW)          // 82944
#define PXP 12544                 // 98 rows * 128
#define FTPROWS 12800             // 100 rows (guard + 98 + guard)

typedef __attribute__((ext_vector_type(8))) short bf16x8;
typedef __attribute__((ext_vector_type(4))) float f32x4;
typedef __attribute__((ext_vector_type(8))) unsigned short u16x8;

__device__ __forceinline__ unsigned short f2bf(float f) {
  unsigned int u = __float_as_uint(f);
  u += 0x7FFFu + ((u >> 16) & 1u);   // RNE
  return (unsigned short)(u >> 16);
}
__device__ __forceinline__ float bf2f(unsigned short s) {
  return __uint_as_float(((unsigned int)s) << 16);
}

#define GLDS(g, l) __builtin_amdgcn_global_load_lds( \
    (const __attribute__((address_space(1))) unsigned int*)(g), \
    (__attribute__((address_space(3))) unsigned int*)(l), 16, 0, 0)

// ---------------- zero helper ----------------
__global__ void k_zero(unsigned short* p, unsigned int n8) {
  unsigned int i = blockIdx.x * 256 + threadIdx.x;
  if (i < n8) ((u16x8*)p)[i] = (u16x8){0, 0, 0, 0, 0, 0, 0, 0};
}

// ---------------- ftp from concat sources: [b][pxp][C] bf16 ----------------
__global__ void __launch_bounds__(256) k_mkftp_cat(
    const float* __restrict__ lo0, const float* __restrict__ lo1,
    const float* __restrict__ hi, unsigned short* __restrict__ dst,
    int C, int CB) {
  const int b = blockIdx.z;
  const float* lo = b ? lo1 : lo0;
  unsigned short* d = dst + (size_t)b * FTPROWS * C + 128 * C;
  const int px0 = blockIdx.x * 64, c0 = blockIdx.y * 64;
  __shared__ float tile[64][65];
  const int t = threadIdx.x;
#pragma unroll
  for (int rep = 0; rep < 16; ++rep) {
    int idx = rep * 256 + t;
    int cl = idx >> 6, pl = idx & 63;
    int cg = c0 + cl;
    const float* s = (cg < CB) ? (lo + (size_t)cg * HW) : (hi + (size_t)(cg - CB) * HW);
    tile[cl][pl] = s[px0 + pl];
  }
  __syncthreads();
  const int pl = t >> 2, cu = (t & 3) * 16;
  const int px = px0 + pl;
  const int h = px / WIDTH, w = px - h * WIDTH;
  const size_t pxp = (size_t)(h + 1) * 128 + (w + 1);
  u16x8 o0, o1;
#pragma unroll
  for (int j = 0; j < 8; ++j) o0[j] = f2bf(tile[cu + j][pl]);
#pragma unroll
  for (int j = 0; j < 8; ++j) o1[j] = f2bf(tile[cu + 8 + j][pl]);
  unsigned short* p = d + pxp * C + c0 + cu;
  *(u16x8*)p = o0;
  *(u16x8*)(p + 8) = o1;
}

// ---------------- ftp from GN(yh bf16)+ReLU (C=512, CperG=16) --------------
__global__ void __launch_bounds__(256) k_mkftp_gn(
    const unsigned short* __restrict__ yh, const float2* __restrict__ stat,
    const float* __restrict__ gamma, const float* __restrict__ beta,
    unsigned short* __restrict__ dst) {
  const int C = 512;
  const int b = blockIdx.z;
  unsigned short* d = dst + (size_t)b * FTPROWS * C + 128 * C;
  const int px0 = blockIdx.x * 64, c0 = blockIdx.y * 64;
  __shared__ float tile[64][65];
  const int t = threadIdx.x;
#pragma unroll
  for (int rep = 0; rep < 16; ++rep) {
    int idx = rep * 256 + t;
    int cl = idx >> 6, pl = idx & 63;
    int cg = c0 + cl;
    float2 st = stat[b * 32 + (cg >> 4)];
    float v = bf2f(yh[(size_t)b * FSTRIDE + (size_t)cg * HW + px0 + pl]);
    v = (v - st.x) * st.y * gamma[cg] + beta[cg];
    tile[cl][pl] = fmaxf(v, 0.f);
  }
  __syncthreads();
  const int pl = t >> 2, cu = (t & 3) * 16;
  const int px = px0 + pl;
  const int h = px / WIDTH, w = px - h * WIDTH;
  const size_t pxp = (size_t)(h + 1) * 128 + (w + 1);
  u16x8 o0, o1;
#pragma unroll
  for (int j = 0; j < 8; ++j) o0[j] = f2bf(tile[cu + j][pl]);
#pragma unroll
  for (int j = 0; j < 8; ++j) o1[j] = f2bf(tile[cu + 8 + j][pl]);
  unsigned short* p = d + pxp * C + c0 + cu;
  *(u16x8*)p = o0;
  *(u16x8*)(p + 8) = o1;
}

// ------- offconv weights, ALL layers: Wt[lyr][k][oc(32 pad)][c] bf16 -------
__global__ void k_prepW_all(const float* __restrict__ ow0, const float* __restrict__ ow1,
                            const float* __restrict__ ow2, const float* __restrict__ ow3,
                            unsigned short* __restrict__ wt) {
  int i = blockIdx.x * 256 + threadIdx.x;      // < 4*9*32*512
  int lyr = i / 147456, r0 = i % 147456;
  const float* ow = (lyr == 0) ? ow0 : (lyr == 1) ? ow1 : (lyr == 2) ? ow2 : ow3;
  int k = r0 / (32 * 512), r = r0 - k * 32 * 512;
  int oc = r / 512, c = r - oc * 512;
  wt[i] = (oc < 18) ? f2bf(ow[((size_t)oc * 512 + c) * 9 + k]) : (unsigned short)0;
}

// ------- dcgemm weights, ALL layers: Ap[m][k*C+c] = dw[m][c][k] bf16 -------
__global__ void k_prepA_all(const float* __restrict__ dw0, const float* __restrict__ dw1,
                            const float* __restrict__ dw2, const float* __restrict__ dw3,
                            unsigned short* __restrict__ ap) {
  int i = blockIdx.x * 256 + threadIdx.x;      // < 7667712
  int lyr, o, C; size_t base;
  if (i < 7077888) { lyr = i / 2359296; o = i % 2359296; C = 512; base = (size_t)lyr * 2359296; }
  else             { lyr = 3; o = i - 7077888; C = 256; base = 7077888; }
  const float* dw = (lyr == 0) ? dw0 : (lyr == 1) ? dw1 : (lyr == 2) ? dw2 : dw3;
  int K = 9 * C;
  int m = o / K, r = o - m * K;
  int k = r / C, c = r - k * C;
  ap[base + o] = f2bf(dw[((size_t)m * C + c) * 9 + k]);
}

// ---------------- offset conv via MFMA, 2-deep pipeline ----------------
__global__ void __launch_bounds__(256) k_offmm(const unsigned short* __restrict__ ftp,
                                               const unsigned short* __restrict__ Wt,
                                               float* __restrict__ part) {
  const int C = 512;
  __shared__ unsigned short As[2][128 * 64];  // 2 x 16 KB
  __shared__ unsigned short Bs[2][32 * 64];   // 2 x 4 KB
  const int tid = threadIdx.x;
  const int lane = tid & 63, wv = tid >> 6;
  const int b = blockIdx.z, ks = blockIdx.y;
  const int pxp0 = 128 + blockIdx.x * 128;
  const unsigned short* fb = ftp + (size_t)b * FTPROWS * C + 128 * C;

  const int lr = lane >> 3;
  const int lu = lane & 7;
  const int fr = lane & 15, hi = lane >> 4;

  f32x4 acc[2][2];
#pragma unroll
  for (int i = 0; i < 2; ++i)
#pragma unroll
    for (int j = 0; j < 2; ++j) acc[i][j] = (f32x4){0.f, 0.f, 0.f, 0.f};

#define OFFMM_STAGE(S, BUF)                                                   \
  {                                                                           \
    const int k_ = ks * 3 + ((S) >> 3);                                       \
    const int dlt_ = (k_ / 3 - 1) * 128 + (k_ % 3 - 1);                       \
    const int c0_ = ((S) & 7) * 64;                                           \
    _Pragma("unroll")                                                         \
    for (int q = 0; q < 4; ++q) {                                             \
      int row = wv * 32 + q * 8 + lr;                                         \
      int su = lu ^ (row & 7);                                                \
      GLDS(fb + (size_t)(pxp0 + dlt_ + row) * C + c0_ + su * 8,               \
           (char*)&As[BUF][0] + (wv * 32 + q * 8) * 128);                     \
    }                                                                         \
    {                                                                         \
      int row = wv * 8 + lr;                                                  \
      int su = lu ^ (row & 7);                                                \
      GLDS(Wt + ((size_t)k_ * 32 + row) * C + c0_ + su * 8,                   \
           (char*)&Bs[BUF][0] + wv * 8 * 128);                                \
    }                                                                         \
  }

  OFFMM_STAGE(0, 0);
  for (int s = 0; s < 24; ++s) {
    const int cur = s & 1;
    if (s + 1 < 24) {
      OFFMM_STAGE(s + 1, cur ^ 1);
      asm volatile("s_waitcnt vmcnt(5)" ::: "memory");
    } else {
      asm volatile("s_waitcnt vmcnt(0)" ::: "memory");
    }
    __builtin_amdgcn_s_barrier();
#pragma unroll
    for (int kk = 0; kk < 2; ++kk) {
      bf16x8 a[2], bb[2];
#pragma unroll
      for (int i = 0; i < 2; ++i) {
        int row = wv * 32 + i * 16 + fr;
        a[i] = *(const bf16x8*)&As[cur][row * 64 + (((kk * 4 + hi) ^ (row & 7)) * 8)];
      }
#pragma unroll
      for (int j = 0; j < 2; ++j) {
        int row = j * 16 + fr;
        bb[j] = *(const bf16x8*)&Bs[cur][row * 64 + (((kk * 4 + hi) ^ (row & 7)) * 8)];
      }
#pragma unroll
      for (int i = 0; i < 2; ++i)
#pragma unroll
        for (int j = 0; j < 2; ++j)
          acc[i][j] = __builtin_amdgcn_mfma_f32_16x16x32_bf16(a[i], bb[j], acc[i][j], 0, 0, 0);
    }
    __builtin_amdgcn_s_barrier();
  }

  float* pb = part + ((size_t)(b * 3 + ks)) * PXP * 32;
#pragma unroll
  for (int i = 0; i < 2; ++i)
#pragma unroll
    for (int j = 0; j < 2; ++j) {
      int row0 = pxp0 + wv * 32 + i * 16 + hi * 4;
      int col = j * 16 + fr;
#pragma unroll
      for (int q = 0; q < 4; ++q)
        pb[(size_t)(row0 + q) * 32 + col] = acc[i][j][q];
    }
}

// ---------------- bilinear tables ----------------
__global__ void k_table(const float* __restrict__ part, const float* __restrict__ ob,
                        int4* __restrict__ tabi, float4* __restrict__ tabw) {
  int b = blockIdx.z, k = blockIdx.y;
  int px = blockIdx.x * 256 + threadIdx.x;
  int h = px / WIDTH, w = px - h * WIDTH;
  size_t pxp = (size_t)(h + 1) * 128 + (w + 1);
  const float* pb = part + (size_t)b * 3 * PXP * 32 + pxp * 32;
  float dy = ob[2 * k] + pb[2 * k] + pb[(size_t)PXP * 32 + 2 * k] + pb[2 * (size_t)PXP * 32 + 2 * k];
  float dx = ob[2 * k + 1] + pb[2 * k + 1] + pb[(size_t)PXP * 32 + 2 * k + 1] + pb[2 * (size_t)PXP * 32 + 2 * k + 1];
  float py = (float)(h - 1 + k / 3) + dy;
  float pxx = (float)(w - 1 + k % 3) + dx;
  float y0 = floorf(py), x0 = floorf(pxx);
  float ay = py - y0, ax = pxx - x0;
  float wy[2] = {1.f - ay, ay}, wx[2] = {1.f - ax, ax};
  int idx[4]; float wt[4];
#pragma unroll
  for (int t = 0; t < 4; ++t) {
    float oy = y0 + (float)(t >> 1);
    float ox = x0 + (float)(t & 1);
    bool valid = (oy >= 0.f) && (oy <= 95.f) && (ox >= 0.f) && (ox <= 95.f);
    int yi = (int)fminf(fmaxf(oy, 0.f), 95.f);
    int xi = (int)fminf(fmaxf(ox, 0.f), 95.f);
    idx[t] = (yi + 1) * 128 + (xi + 1);
    wt[t] = valid ? wy[t >> 1] * wx[t & 1] : 0.f;
  }
  size_t e = (size_t)b * TABSTRIDE + (size_t)k * HW + px;
  tabi[e] = make_int4(idx[0], idx[1], idx[2], idx[3]);
  tabw[e] = make_float4(wt[0], wt[1], wt[2], wt[3]);
}

// ---------------- sampled from ftp: samp[px][kloc*C+c] (R13-verified) ------
__global__ void __launch_bounds__(256) k_sample_t(
    const unsigned short* __restrict__ ftp,
    const int4* __restrict__ tabi, const float4* __restrict__ tabw,
    unsigned short* __restrict__ samp, int C, int kbase, int rowK) {
  const int z = blockIdx.z;
  const int b = z & 1, kloc = z >> 1;
  const int k = kbase + kloc;
  const int t = threadIdx.x;
  const int px = blockIdx.x * 64 + (t >> 2);
  const int c = blockIdx.y * 64 + (t & 3) * 16;
  const unsigned short* fb = ftp + (size_t)b * FTPROWS * C + 128 * C;
  size_t e = (size_t)b * TABSTRIDE + (size_t)k * HW + px;
  int4 id = tabi[e];
  float4 wt = tabw[e];
  float acc[16];
#pragma unroll
  for (int j = 0; j < 16; ++j) acc[j] = 0.f;
  const int ids[4] = {id.x, id.y, id.z, id.w};
  const float wts[4] = {wt.x, wt.y, wt.z, wt.w};
#pragma unroll
  for (int s = 0; s < 4; ++s) {
    const unsigned short* p = fb + (size_t)ids[s] * C + c;
    u16x8 v0 = *(const u16x8*)p;
    u16x8 v1 = *(const u16x8*)(p + 8);
    float wgt = wts[s];
#pragma unroll
    for (int j = 0; j < 8; ++j) acc[j] += wgt * bf2f(v0[j]);
#pragma unroll
    for (int j = 0; j < 8; ++j) acc[8 + j] += wgt * bf2f(v1[j]);
  }
  u16x8 o0, o1;
#pragma unroll
  for (int j = 0; j < 8; ++j) o0[j] = f2bf(acc[j]);
#pragma unroll
  for (int j = 0; j < 8; ++j) o1[j] = f2bf(acc[8 + j]);
  unsigned short* dst = samp + ((size_t)b * HW + px) * rowK + kloc * C + c;
  *(u16x8*)dst = o0;
  *(u16x8*)(dst + 8) = o1;
}

// ---- staging 128x96 BK=32: A=8 units, B=6 units; w0,w1:2A+2B; w2,w3:2A+1B --
__device__ __forceinline__ void stage_ab96(const unsigned short* __restrict__ Ag,
                                           const unsigned short* __restrict__ Bg,
                                           int lda, int rowK, int kt,
                                           unsigned short* as_, unsigned short* bs_,
                                           int wv, int lane) {
  const int lr = lane >> 2;
  const int lu = lane & 3;
#pragma unroll
  for (int q = 0; q < 2; ++q) {
    int row = wv * 32 + q * 16 + lr;
    int su = lu ^ ((row >> 1) & 3);
    GLDS(Ag + (size_t)row * lda + kt + su * 8, (char*)as_ + (wv * 2 + q) * 1024);
  }
  const int nb = (wv < 2) ? 2 : 1;
  const int bu0 = (wv < 2) ? (2 * wv) : (wv + 2);
  for (int q = 0; q < nb; ++q) {
    int unit = bu0 + q;
    int row = unit * 16 + lr;
    int su = lu ^ ((row >> 1) & 3);
    GLDS(Bg + (size_t)row * rowK + kt + su * 8, (char*)bs_ + unit * 1024);
  }
}

// ---------------- bf16 MFMA GEMM: 128m x 96n, BK=32, 3-stage, bf16 Y -------
// (R11/R13-verified: 4 waves of 64m x 48n, occupancy ~30%)
__global__ void __launch_bounds__(256) k_dcgemm(
    const unsigned short* __restrict__ Ap, const unsigned short* __restrict__ Bt,
    unsigned short* __restrict__ Yh, float2* __restrict__ gnp,
    int lda, int rowK, int aOff, int accum, int CperG, int dogn) {
  __shared__ unsigned short As[3][128 * 32];
  __shared__ unsigned short Bs[3][96 * 32];
  const int tid = threadIdx.x;
  const int lane = tid & 63, wv = tid >> 6;

  const int nwg = gridDim.x;
  const int cpx = nwg >> 3;
  const int bid = blockIdx.x;
  const int l = (bid & 7) * cpx + (bid >> 3);
  const int nm = nwg / 192;
  const int m_i = l % nm;
  const int rest = l / nm;
  const int n_i = rest % 96;
  const int b = rest / 96;

  const int m0 = m_i << 7, n0 = n_i * 96;
  const unsigned short* Ag = Ap + (size_t)m0 * lda + aOff;
  const unsigned short* Bg = Bt + ((size_t)b * HW + n0) * rowK;

  const int wm = (wv >> 1) * 64, wn = (wv & 1) * 48;
  const int fr = lane & 15, hi = lane >> 4;
  const int nt = rowK >> 5;

  f32x4 acc[4][3];
#pragma unroll
  for (int i = 0; i < 4; ++i)
#pragma unroll
    for (int j = 0; j < 3; ++j) acc[i][j] = (f32x4){0.f, 0.f, 0.f, 0.f};

  stage_ab96(Ag, Bg, lda, rowK, 0,  &As[0][0], &Bs[0][0], wv, lane);
  stage_ab96(Ag, Bg, lda, rowK, 32, &As[1][0], &Bs[1][0], wv, lane);

  for (int t = 0; t < nt; ++t) {
    const int cur = t % 3;
    if (t + 2 < nt) {
      stage_ab96(Ag, Bg, lda, rowK, (t + 2) << 5, &As[(t + 2) % 3][0],
                 &Bs[(t + 2) % 3][0], wv, lane);
      if (wv < 2) asm volatile("s_waitcnt vmcnt(8)" ::: "memory");
      else        asm volatile("s_waitcnt vmcnt(6)" ::: "memory");
    } else if (t + 1 < nt) {
      if (wv < 2) asm volatile("s_waitcnt vmcnt(4)" ::: "memory");
      else        asm volatile("s_waitcnt vmcnt(3)" ::: "memory");
    } else {
      asm volatile("s_waitcnt vmcnt(0)" ::: "memory");
    }
    __builtin_amdgcn_s_barrier();
    __builtin_amdgcn_sched_barrier(0);
    bf16x8 a[4], bb[3];
#pragma unroll
    for (int i = 0; i < 4; ++i) {
      int row = wm + i * 16 + fr;
      a[i] = *(const bf16x8*)&As[cur][row * 32 + ((hi ^ ((row >> 1) & 3)) * 8)];
    }
#pragma unroll
    for (int j = 0; j < 3; ++j) {
      int row = wn + j * 16 + fr;
      bb[j] = *(const bf16x8*)&Bs[cur][row * 32 + ((hi ^ ((row >> 1) & 3)) * 8)];
    }
    __builtin_amdgcn_s_setprio(1);
#pragma unroll
    for (int i = 0; i < 4; ++i)
#pragma unroll
      for (int j = 0; j < 3; ++j)
        acc[i][j] = __builtin_amdgcn_mfma_f32_16x16x32_bf16(a[i], bb[j], acc[i][j], 0, 0, 0);
    __builtin_amdgcn_s_setprio(0);
    __builtin_amdgcn_s_barrier();
  }

  unsigned short* Yb = Yh + (size_t)b * FSTRIDE;
  const int orow = m0 + wm + hi * 4;
  const int ocol = n0 + wn + fr;
  float s_[4], q_[4];
#pragma unroll
  for (int i = 0; i < 4; ++i) { s_[i] = 0.f; q_[i] = 0.f; }
#pragma unroll
  for (int i = 0; i < 4; ++i) {
#pragma unroll
    for (int j = 0; j < 3; ++j) {
      unsigned short* p = Yb + (size_t)(orow + i * 16) * HW + ocol + j * 16;
#pragma unroll
      for (int q = 0; q < 4; ++q) {
        float v = acc[i][j][q];
        if (accum) v += bf2f(p[(size_t)q * HW]);
        p[(size_t)q * HW] = f2bf(v);
        s_[i] += v;
        q_[i] += v * v;
      }
    }
  }

  if (dogn) {
    const int redmax = (CperG == 16) ? 32 : 16;
#pragma unroll
    for (int i = 0; i < 4; ++i) {
      float s = s_[i], q = q_[i];
      for (int off = 1; off <= redmax; off <<= 1) {
        s += __shfl_xor(s, off);
        q += __shfl_xor(q, off);
      }
      int row0 = m0 + wm + i * 16 + ((CperG == 8) ? (lane >> 5) * 8 : 0);
      int g = row0 / CperG;
      bool writer = (CperG == 16) ? (lane == 0) : ((lane & 31) == 0);
      if (writer)
        gnp[(((size_t)(b * 32 + g)) * 96 + n_i) * 2 + (wv & 1)] = make_float2(s, q);
    }
  }
}

// ---------------- GN finalize from dcgemm partials (192 slots/group) -------
__global__ void k_gnfin2(const float2* __restrict__ gnp, float2* __restrict__ stat,
                         int CperG) {
  int t = threadIdx.x;  // 0..63 = b*32+g
  float s = 0.f, q = 0.f;
  for (int j = 0; j < 192; ++j) {
    float2 v = gnp[(size_t)t * 192 + j];
    s += v.x; q += v.y;
  }
  float n = (float)(CperG * HW);
  float m = s / n;
  float var = q / n - m * m;
  stat[t] = make_float2(m, rsqrtf(var + 1e-5f));
}

// ---------------- fallback GN stats from yh (3-chunk path only) ------------
__global__ void __launch_bounds__(256) k_gnstats1h(const unsigned short* __restrict__ yh,
                                                   float2* __restrict__ part, int CperG) {
  const int b = blockIdx.z, g = blockIdx.x, ch = blockIdx.y;
  const int n = CperG * HW;
  const int cs8 = (n >> 4) >> 3;
  const u16x8* p = (const u16x8*)(yh + (size_t)b * FSTRIDE + (size_t)g * n + (size_t)ch * (n >> 4));
  float s = 0.f, q = 0.f;
  for (int i = threadIdx.x; i < cs8; i += 256) {
    u16x8 v = p[i];
#pragma unroll
    for (int j = 0; j < 8; ++j) { float f = bf2f(v[j]); s += f; q += f * f; }
  }
  __shared__ float ss[256], qs[256];
  ss[threadIdx.x] = s; qs[threadIdx.x] = q;
  __syncthreads();
  for (int d = 128; d > 0; d >>= 1) {
    if (threadIdx.x < d) { ss[threadIdx.x] += ss[threadIdx.x + d]; qs[threadIdx.x] += qs[threadIdx.x + d]; }
    __syncthreads();
  }
  if (threadIdx.x == 0) part[((b << 5) + g) * 16 + ch] = make_float2(ss[0], qs[0]);
}

__global__ void k_gnfin(const float2* __restrict__ part, float2* __restrict__ stat,
                        int CperG) {
  int t = threadIdx.x;
  float s = 0.f, q = 0.f;
#pragma unroll
  for (int j = 0; j < 16; ++j) { float2 v = part[t * 16 + j]; s += v.x; q += v.y; }
  float n = (float)(CperG * HW);
  float m = s / n;
  float var = q / n - m * m;
  stat[t] = make_float2(m, rsqrtf(var + 1e-5f));
}

// ------- fused layer-4 GN-apply + cosine partials ----------
__global__ void __launch_bounds__(256) k_gncos(
    const unsigned short* __restrict__ yh, const float2* __restrict__ stat,
    const float* __restrict__ gamma, const float* __restrict__ beta,
    float* __restrict__ res, float4* __restrict__ cospart) {
  int px = blockIdx.x * 256 + threadIdx.x;
  int cc = blockIdx.y;
  float saa = 0.f, sbb = 0.f, sab = 0.f;
  for (int c = cc * 32; c < cc * 32 + 32; ++c) {
    float2 st0 = stat[c >> 3];
    float2 st1 = stat[32 + (c >> 3)];
    float ga = gamma[c], be = beta[c];
    float a = fmaxf((bf2f(yh[(size_t)c * HW + px]) - st0.x) * st0.y * ga + be, 0.f);
    float b = fmaxf((bf2f(yh[(size_t)FSTRIDE + (size_t)c * HW + px]) - st1.x) * st1.y * ga + be, 0.f);
    res[(size_t)c * HW + px] = a;
    res[(size_t)RSTRIDE + (size_t)c * HW + px] = b;
    saa += a * a; sbb += b * b; sab += a * b;
  }
  cospart[(size_t)cc * HW + px] = make_float4(saa, sbb, sab, 0.f);
}

__global__ void k_cos2(const float4* __restrict__ part, float* __restrict__ wpix) {
  int px = blockIdx.x * 256 + threadIdx.x;
  float saa = 0.f, sbb = 0.f, sab = 0.f;
#pragma unroll
  for (int cc = 0; cc < 8; ++cc) {
    float4 v = part[(size_t)cc * HW + px];
    saa += v.x; sbb += v.y; sab += v.z;
  }
  float na = sqrtf(saa), nb = sqrtf(sbb);
  float ttw = saa / fmaxf(na * na, 1e-8f);
  float tkw = sab / fmaxf(na * nb, 1e-8f);
  float m = fmaxf(ttw, tkw);
  float e0 = expf(ttw - m), e1 = expf(tkw - m);
  wpix[px] = e0 / (e0 + e1);
}

__global__ void k_combine(const float* __restrict__ res, const float* __restrict__ wpix,
                          float* __restrict__ out) {
  int i = blockIdx.x * 256 + threadIdx.x;
  int px = i % HW;
  float w0 = wpix[px];
  out[i] = w0 * res[i] + (1.f - w0) * res[(size_t)RSTRIDE + i];
}

extern "C" void kernel_launch(void* const* d_in, const int* in_sizes, int n_in,
                              void* d_out, int out_size, void* d_ws, size_t ws_size,
                              hipStream_t stream) {
  const float* datas = (const float*)d_in[0];
  const float* ow[4] = {(const float*)d_in[1], (const float*)d_in[6],
                        (const float*)d_in[11], (const float*)d_in[16]};
  const float* ob[4] = {(const float*)d_in[2], (const float*)d_in[7],
                        (const float*)d_in[12], (const float*)d_in[17]};
  const float* dw[4] = {(const float*)d_in[3], (const float*)d_in[8],
                        (const float*)d_in[13], (const float*)d_in[18]};
  const float* gg[4] = {(const float*)d_in[4], (const float*)d_in[9],
                        (const float*)d_in[14], (const float*)d_in[19]};
  const float* gb[4] = {(const float*)d_in[5], (const float*)d_in[10],
                        (const float*)d_in[15], (const float*)d_in[20]};

  // full-K layout needs ~247.8 MB (all-layer Ap/Wt hoisted); else 3-chunk.
  const int fullk = (ws_size >= 248500000ull) ? 1 : 0;
  const size_t sampN = fullk ? (2 * (size_t)HW * 4608) : (2 * (size_t)HW * 1536);

  float* ws = (float*)d_ws;
  unsigned short* yh = (unsigned short*)ws;               // 2*FSTRIDE bf16
  float* offp3 = ws + (2 * (size_t)FSTRIDE * 2) / 4;      // 2*3*PXP*32 fp32
  float4* tabw = (float4*)(offp3 + 2 * 3 * (size_t)PXP * 32);
  int4*   tabi = (int4*)(tabw + 2 * (size_t)TABSTRIDE);
  float* wpix = (float*)(tabi + 2 * (size_t)TABSTRIDE);   // HW
  float2* stat = (float2*)(wpix + HW);                    // 64
  float2* gnp  = stat + 64;                               // 2*32*96*2 float2
  float2* gnpart = gnp + 2 * 32 * 96 * 2;                 // 1024 (fallback)
  float4* cospart = (float4*)(gnpart + 1024);             // 8*HW
  float* endp = (float*)(cospart + 8 * (size_t)HW);
  size_t ofs = ((size_t)(endp - ws) + 3) & ~(size_t)3;
  unsigned short* samp = (unsigned short*)(ws + ofs);
  unsigned short* apAll = samp + sampN;                   // 7667712 us
  unsigned short* wtAll = apAll + (size_t)7667712;        // 589824 us
  unsigned short* ftp512 = wtAll + (size_t)589824;        // 2*FTPROWS*512
  unsigned short* ftp256 = fullk ? (samp + 2 * (size_t)HW * 2304)
                                 : (ftp512 + 2 * (size_t)FTPROWS * 512);
  float* res = (float*)(ftp256 + 2 * (size_t)FTPROWS * 256);

  dim3 blk(256);
  k_zero<<<dim3(2 * FTPROWS * 512 / 8 / 256), blk, 0, stream>>>(ftp512, 2u * FTPROWS * 512 / 8);
  k_prepA_all<<<dim3(29952), blk, 0, stream>>>(dw[0], dw[1], dw[2], dw[3], apAll);
  k_prepW_all<<<dim3(2304), blk, 0, stream>>>(ow[0], ow[1], ow[2], ow[3], wtAll);

  for (int lyr = 0; lyr < 4; ++lyr) {
    const int Cx = (lyr < 3) ? 512 : 256;
    const int M  = Cx;
    const int CperG = (lyr < 3) ? 16 : 8;
    const unsigned short* Ap = (lyr < 3) ? (apAll + (size_t)lyr * 2359296)
                                         : (apAll + (size_t)7077888);
    const unsigned short* Wt = wtAll + (size_t)lyr * 147456;
    if (lyr == 0) {
      k_mkftp_cat<<<dim3(144, 8, 2), blk, 0, stream>>>(datas + RSTRIDE, datas,
                                                       datas + RSTRIDE, ftp512, 512, 256);
    } else {
      k_mkftp_gn<<<dim3(144, 8, 2), blk, 0, stream>>>(yh, stat, gg[lyr - 1], gb[lyr - 1],
                                                      ftp512);
    }
    k_offmm<<<dim3(96, 3, 2), blk, 0, stream>>>(ftp512, Wt, offp3);
    k_table<<<dim3(36, 9, 2), blk, 0, stream>>>(offp3, ob[lyr], tabi, tabw);
    const unsigned short* sftp;
    if (lyr < 3) {
      sftp = ftp512;
    } else {
      k_zero<<<dim3(2 * FTPROWS * 256 / 8 / 256), blk, 0, stream>>>(ftp256, 2u * FTPROWS * 256 / 8);
      k_mkftp_cat<<<dim3(144, 4, 2), blk, 0, stream>>>(datas + RSTRIDE, datas,
                                                       datas, ftp256, 256, 256);
      sftp = ftp256;
    }
    const int nch = fullk ? 1 : 3;
    const int nk = 9 / nch;
    const int rowK = nk * Cx;
    for (int ch = 0; ch < nch; ++ch) {
      k_sample_t<<<dim3(144, Cx / 64, 2 * nk), blk, 0, stream>>>(sftp, tabi, tabw, samp,
                                                                 Cx, ch * nk, rowK);
      k_dcgemm<<<dim3((M / 128) * 96 * 2), blk, 0, stream>>>(
          Ap, samp, yh, gnp, 9 * Cx, rowK, ch * rowK, ch > 0, CperG,
          fullk && (ch == nch - 1));
    }
    if (fullk) {
      k_gnfin2<<<dim3(1), dim3(64), 0, stream>>>(gnp, stat, CperG);
    } else {
      k_gnstats1h<<<dim3(32, 16, 2), blk, 0, stream>>>(yh, gnpart, CperG);
      k_gnfin<<<dim3(1), dim3(64), 0, stream>>>(gnpart, stat, CperG);
    }
  }

  // layer-4 fused GN-apply + cosine partials, then blend
  k_gncos<<<dim3(36, 8), blk, 0, stream>>>(yh, stat, gg[3], gb[3], res, cospart);
  k_cos2<<<dim3(36), blk, 0, stream>>>(cospart, wpix);
  k_combine<<<dim3(RSTRIDE / 256), blk, 0, stream>>>(res, wpix, (float*)d_out);
}

// Round 16
// 889.613 us; speedup vs baseline: 1.1911x; 1.0919x over previous
//
#include <hip/hip_runtime.h>
#include <math.h>

#define HW 9216
#define WIDTH 96
#define FSTRIDE (512*HW)          // 4718592
#define RSTRIDE (256*HW)          // 2359296
#define TABSTRIDE (9*HW)          // 82944
#define PXP 12544                 // 98 rows * 128
#define FTPROWS 12800             // 100 rows (guard + 98 + guard)

typedef __attribute__((ext_vector_type(8))) short bf16x8;
typedef __attribute__((ext_vector_type(4))) float f32x4;
typedef __attribute__((ext_vector_type(8))) unsigned short u16x8;

__device__ __forceinline__ unsigned short f2bf(float f) {
  unsigned int u = __float_as_uint(f);
  u += 0x7FFFu + ((u >> 16) & 1u);   // RNE
  return (unsigned short)(u >> 16);
}
__device__ __forceinline__ float bf2f(unsigned short s) {
  return __uint_as_float(((unsigned int)s) << 16);
}

#define GLDS(g, l) __builtin_amdgcn_global_load_lds( \
    (const __attribute__((address_space(1))) unsigned int*)(g), \
    (__attribute__((address_space(3))) unsigned int*)(l), 16, 0, 0)

// ---------------- zero helper ----------------
__global__ void k_zero(unsigned short* p, unsigned int n8) {
  unsigned int i = blockIdx.x * 256 + threadIdx.x;
  if (i < n8) ((u16x8*)p)[i] = (u16x8){0, 0, 0, 0, 0, 0, 0, 0};
}

// ---------------- ftp from concat sources: [b][pxp][C] bf16 ----------------
__global__ void __launch_bounds__(256) k_mkftp_cat(
    const float* __restrict__ lo0, const float* __restrict__ lo1,
    const float* __restrict__ hi, unsigned short* __restrict__ dst,
    int C, int CB) {
  const int b = blockIdx.z;
  const float* lo = b ? lo1 : lo0;
  unsigned short* d = dst + (size_t)b * FTPROWS * C + 128 * C;
  const int px0 = blockIdx.x * 64, c0 = blockIdx.y * 64;
  __shared__ float tile[64][65];
  const int t = threadIdx.x;
#pragma unroll
  for (int rep = 0; rep < 16; ++rep) {
    int idx = rep * 256 + t;
    int cl = idx >> 6, pl = idx & 63;
    int cg = c0 + cl;
    const float* s = (cg < CB) ? (lo + (size_t)cg * HW) : (hi + (size_t)(cg - CB) * HW);
    tile[cl][pl] = s[px0 + pl];
  }
  __syncthreads();
  const int pl = t >> 2, cu = (t & 3) * 16;
  const int px = px0 + pl;
  const int h = px / WIDTH, w = px - h * WIDTH;
  const size_t pxp = (size_t)(h + 1) * 128 + (w + 1);
  u16x8 o0, o1;
#pragma unroll
  for (int j = 0; j < 8; ++j) o0[j] = f2bf(tile[cu + j][pl]);
#pragma unroll
  for (int j = 0; j < 8; ++j) o1[j] = f2bf(tile[cu + 8 + j][pl]);
  unsigned short* p = d + pxp * C + c0 + cu;
  *(u16x8*)p = o0;
  *(u16x8*)(p + 8) = o1;
}

// ---------------- ftp from GN(yh bf16)+ReLU (C=512, CperG=16) --------------
__global__ void __launch_bounds__(256) k_mkftp_gn(
    const unsigned short* __restrict__ yh, const float2* __restrict__ stat,
    const float* __restrict__ gamma, const float* __restrict__ beta,
    unsigned short* __restrict__ dst) {
  const int C = 512;
  const int b = blockIdx.z;
  unsigned short* d = dst + (size_t)b * FTPROWS * C + 128 * C;
  const int px0 = blockIdx.x * 64, c0 = blockIdx.y * 64;
  __shared__ float tile[64][65];
  const int t = threadIdx.x;
#pragma unroll
  for (int rep = 0; rep < 16; ++rep) {
    int idx = rep * 256 + t;
    int cl = idx >> 6, pl = idx & 63;
    int cg = c0 + cl;
    float2 st = stat[b * 32 + (cg >> 4)];
    float v = bf2f(yh[(size_t)b * FSTRIDE + (size_t)cg * HW + px0 + pl]);
    v = (v - st.x) * st.y * gamma[cg] + beta[cg];
    tile[cl][pl] = fmaxf(v, 0.f);
  }
  __syncthreads();
  const int pl = t >> 2, cu = (t & 3) * 16;
  const int px = px0 + pl;
  const int h = px / WIDTH, w = px - h * WIDTH;
  const size_t pxp = (size_t)(h + 1) * 128 + (w + 1);
  u16x8 o0, o1;
#pragma unroll
  for (int j = 0; j < 8; ++j) o0[j] = f2bf(tile[cu + j][pl]);
#pragma unroll
  for (int j = 0; j < 8; ++j) o1[j] = f2bf(tile[cu + 8 + j][pl]);
  unsigned short* p = d + pxp * C + c0 + cu;
  *(u16x8*)p = o0;
  *(u16x8*)(p + 8) = o1;
}

// ------- offconv weights, ALL layers: Wt[lyr][k][oc(32 pad)][c] bf16 -------
__global__ void k_prepW_all(const float* __restrict__ ow0, const float* __restrict__ ow1,
                            const float* __restrict__ ow2, const float* __restrict__ ow3,
                            unsigned short* __restrict__ wt) {
  int i = blockIdx.x * 256 + threadIdx.x;      // < 4*9*32*512
  int lyr = i / 147456, r0 = i % 147456;
  const float* ow = (lyr == 0) ? ow0 : (lyr == 1) ? ow1 : (lyr == 2) ? ow2 : ow3;
  int k = r0 / (32 * 512), r = r0 - k * 32 * 512;
  int oc = r / 512, c = r - oc * 512;
  wt[i] = (oc < 18) ? f2bf(ow[((size_t)oc * 512 + c) * 9 + k]) : (unsigned short)0;
}

// ------- dcgemm weights, ALL layers: Ap[m][k*C+c] = dw[m][c][k] bf16 -------
__global__ void k_prepA_all(const float* __restrict__ dw0, const float* __restrict__ dw1,
                            const float* __restrict__ dw2, const float* __restrict__ dw3,
                            unsigned short* __restrict__ ap) {
  int i = blockIdx.x * 256 + threadIdx.x;      // < 7667712
  int lyr, o, C; size_t base;
  if (i < 7077888) { lyr = i / 2359296; o = i % 2359296; C = 512; base = (size_t)lyr * 2359296; }
  else             { lyr = 3; o = i - 7077888; C = 256; base = 7077888; }
  const float* dw = (lyr == 0) ? dw0 : (lyr == 1) ? dw1 : (lyr == 2) ? dw2 : dw3;
  int K = 9 * C;
  int m = o / K, r = o - m * K;
  int k = r / C, c = r - k * C;
  ap[base + o] = f2bf(dw[((size_t)m * C + c) * 9 + k]);
}

// ---------------- offset conv via MFMA, 2-deep pipeline ----------------
__global__ void __launch_bounds__(256) k_offmm(const unsigned short* __restrict__ ftp,
                                               const unsigned short* __restrict__ Wt,
                                               float* __restrict__ part) {
  const int C = 512;
  __shared__ unsigned short As[2][128 * 64];  // 2 x 16 KB
  __shared__ unsigned short Bs[2][32 * 64];   // 2 x 4 KB
  const int tid = threadIdx.x;
  const int lane = tid & 63, wv = tid >> 6;
  const int b = blockIdx.z, ks = blockIdx.y;
  const int pxp0 = 128 + blockIdx.x * 128;
  const unsigned short* fb = ftp + (size_t)b * FTPROWS * C + 128 * C;

  const int lr = lane >> 3;
  const int lu = lane & 7;
  const int fr = lane & 15, hi = lane >> 4;

  f32x4 acc[2][2];
#pragma unroll
  for (int i = 0; i < 2; ++i)
#pragma unroll
    for (int j = 0; j < 2; ++j) acc[i][j] = (f32x4){0.f, 0.f, 0.f, 0.f};

#define OFFMM_STAGE(S, BUF)                                                   \
  {                                                                           \
    const int k_ = ks * 3 + ((S) >> 3);                                       \
    const int dlt_ = (k_ / 3 - 1) * 128 + (k_ % 3 - 1);                       \
    const int c0_ = ((S) & 7) * 64;                                           \
    _Pragma("unroll")                                                         \
    for (int q = 0; q < 4; ++q) {                                             \
      int row = wv * 32 + q * 8 + lr;                                         \
      int su = lu ^ (row & 7);                                                \
      GLDS(fb + (size_t)(pxp0 + dlt_ + row) * C + c0_ + su * 8,               \
           (char*)&As[BUF][0] + (wv * 32 + q * 8) * 128);                     \
    }                                                                         \
    {                                                                         \
      int row = wv * 8 + lr;                                                  \
      int su = lu ^ (row & 7);                                                \
      GLDS(Wt + ((size_t)k_ * 32 + row) * C + c0_ + su * 8,                   \
           (char*)&Bs[BUF][0] + wv * 8 * 128);                                \
    }                                                                         \
  }

  OFFMM_STAGE(0, 0);
  for (int s = 0; s < 24; ++s) {
    const int cur = s & 1;
    if (s + 1 < 24) {
      OFFMM_STAGE(s + 1, cur ^ 1);
      asm volatile("s_waitcnt vmcnt(5)" ::: "memory");
    } else {
      asm volatile("s_waitcnt vmcnt(0)" ::: "memory");
    }
    __builtin_amdgcn_s_barrier();
#pragma unroll
    for (int kk = 0; kk < 2; ++kk) {
      bf16x8 a[2], bb[2];
#pragma unroll
      for (int i = 0; i < 2; ++i) {
        int row = wv * 32 + i * 16 + fr;
        a[i] = *(const bf16x8*)&As[cur][row * 64 + (((kk * 4 + hi) ^ (row & 7)) * 8)];
      }
#pragma unroll
      for (int j = 0; j < 2; ++j) {
        int row = j * 16 + fr;
        bb[j] = *(const bf16x8*)&Bs[cur][row * 64 + (((kk * 4 + hi) ^ (row & 7)) * 8)];
      }
#pragma unroll
      for (int i = 0; i < 2; ++i)
#pragma unroll
        for (int j = 0; j < 2; ++j)
          acc[i][j] = __builtin_amdgcn_mfma_f32_16x16x32_bf16(a[i], bb[j], acc[i][j], 0, 0, 0);
    }
    __builtin_amdgcn_s_barrier();
  }

  float* pb = part + ((size_t)(b * 3 + ks)) * PXP * 32;
#pragma unroll
  for (int i = 0; i < 2; ++i)
#pragma unroll
    for (int j = 0; j < 2; ++j) {
      int row0 = pxp0 + wv * 32 + i * 16 + hi * 4;
      int col = j * 16 + fr;
#pragma unroll
      for (int q = 0; q < 4; ++q)
        pb[(size_t)(row0 + q) * 32 + col] = acc[i][j][q];
    }
}

// ---------------- bilinear tables ----------------
__global__ void k_table(const float* __restrict__ part, const float* __restrict__ ob,
                        int4* __restrict__ tabi, float4* __restrict__ tabw) {
  int b = blockIdx.z, k = blockIdx.y;
  int px = blockIdx.x * 256 + threadIdx.x;
  int h = px / WIDTH, w = px - h * WIDTH;
  size_t pxp = (size_t)(h + 1) * 128 + (w + 1);
  const float* pb = part + (size_t)b * 3 * PXP * 32 + pxp * 32;
  float dy = ob[2 * k] + pb[2 * k] + pb[(size_t)PXP * 32 + 2 * k] + pb[2 * (size_t)PXP * 32 + 2 * k];
  float dx = ob[2 * k + 1] + pb[2 * k + 1] + pb[(size_t)PXP * 32 + 2 * k + 1] + pb[2 * (size_t)PXP * 32 + 2 * k + 1];
  float py = (float)(h - 1 + k / 3) + dy;
  float pxx = (float)(w - 1 + k % 3) + dx;
  float y0 = floorf(py), x0 = floorf(pxx);
  float ay = py - y0, ax = pxx - x0;
  float wy[2] = {1.f - ay, ay}, wx[2] = {1.f - ax, ax};
  int idx[4]; float wt[4];
#pragma unroll
  for (int t = 0; t < 4; ++t) {
    float oy = y0 + (float)(t >> 1);
    float ox = x0 + (float)(t & 1);
    bool valid = (oy >= 0.f) && (oy <= 95.f) && (ox >= 0.f) && (ox <= 95.f);
    int yi = (int)fminf(fmaxf(oy, 0.f), 95.f);
    int xi = (int)fminf(fmaxf(ox, 0.f), 95.f);
    idx[t] = (yi + 1) * 128 + (xi + 1);
    wt[t] = valid ? wy[t >> 1] * wx[t & 1] : 0.f;
  }
  size_t e = (size_t)b * TABSTRIDE + (size_t)k * HW + px;
  tabi[e] = make_int4(idx[0], idx[1], idx[2], idx[3]);
  tabw[e] = make_float4(wt[0], wt[1], wt[2], wt[3]);
}

// ---- sampled from ftp: R13-verified BODY, XCD-chunked 1D grid (T1 only) ---
// nwg = 144*(C/64)*2*nk; logical l: c-chunk inner, px mid, (b,k) outer.
__global__ void __launch_bounds__(256) k_sample_t(
    const unsigned short* __restrict__ ftp,
    const int4* __restrict__ tabi, const float4* __restrict__ tabw,
    unsigned short* __restrict__ samp, int C, int kbase, int rowK, int yc) {
  const int nwg = gridDim.x;
  const int cpx = nwg >> 3;
  const int bid = blockIdx.x;
  const int l = (bid & 7) * cpx + (bid >> 3);
  const int ci = l % yc;
  const int r = l / yc;
  const int pxi = r % 144;
  const int zk = r / 144;
  const int b = zk & 1, kloc = zk >> 1;
  const int k = kbase + kloc;
  const int t = threadIdx.x;
  const int px = pxi * 64 + (t >> 2);
  const int c = ci * 64 + (t & 3) * 16;
  const unsigned short* fb = ftp + (size_t)b * FTPROWS * C + 128 * C;
  size_t e = (size_t)b * TABSTRIDE + (size_t)k * HW + px;
  int4 id = tabi[e];
  float4 wt = tabw[e];
  float acc[16];
#pragma unroll
  for (int j = 0; j < 16; ++j) acc[j] = 0.f;
  const int ids[4] = {id.x, id.y, id.z, id.w};
  const float wts[4] = {wt.x, wt.y, wt.z, wt.w};
#pragma unroll
  for (int s = 0; s < 4; ++s) {
    const unsigned short* p = fb + (size_t)ids[s] * C + c;
    u16x8 v0 = *(const u16x8*)p;
    u16x8 v1 = *(const u16x8*)(p + 8);
    float wgt = wts[s];
#pragma unroll
    for (int j = 0; j < 8; ++j) acc[j] += wgt * bf2f(v0[j]);
#pragma unroll
    for (int j = 0; j < 8; ++j) acc[8 + j] += wgt * bf2f(v1[j]);
  }
  u16x8 o0, o1;
#pragma unroll
  for (int j = 0; j < 8; ++j) o0[j] = f2bf(acc[j]);
#pragma unroll
  for (int j = 0; j < 8; ++j) o1[j] = f2bf(acc[8 + j]);
  unsigned short* dst = samp + ((size_t)b * HW + px) * rowK + kloc * C + c;
  *(u16x8*)dst = o0;
  *(u16x8*)(dst + 8) = o1;
}

// ---- staging 128x96 BK=32: A=8 units, B=6 units; w0,w1:2A+2B; w2,w3:2A+1B --
__device__ __forceinline__ void stage_ab96(const unsigned short* __restrict__ Ag,
                                           const unsigned short* __restrict__ Bg,
                                           int lda, int rowK, int kt,
                                           unsigned short* as_, unsigned short* bs_,
                                           int wv, int lane) {
  const int lr = lane >> 2;
  const int lu = lane & 3;
#pragma unroll
  for (int q = 0; q < 2; ++q) {
    int row = wv * 32 + q * 16 + lr;
    int su = lu ^ ((row >> 1) & 3);
    GLDS(Ag + (size_t)row * lda + kt + su * 8, (char*)as_ + (wv * 2 + q) * 1024);
  }
  const int nb = (wv < 2) ? 2 : 1;
  const int bu0 = (wv < 2) ? (2 * wv) : (wv + 2);
  for (int q = 0; q < nb; ++q) {
    int unit = bu0 + q;
    int row = unit * 16 + lr;
    int su = lu ^ ((row >> 1) & 3);
    GLDS(Bg + (size_t)row * rowK + kt + su * 8, (char*)bs_ + unit * 1024);
  }
}

// ---------------- bf16 MFMA GEMM: 128m x 96n, BK=32, 3-stage, bf16 Y -------
// (R11/R13/R15-verified: 4 waves of 64m x 48n, occupancy ~30%)
__global__ void __launch_bounds__(256) k_dcgemm(
    const unsigned short* __restrict__ Ap, const unsigned short* __restrict__ Bt,
    unsigned short* __restrict__ Yh, float2* __restrict__ gnp,
    int lda, int rowK, int aOff, int accum, int CperG, int dogn) {
  __shared__ unsigned short As[3][128 * 32];
  __shared__ unsigned short Bs[3][96 * 32];
  const int tid = threadIdx.x;
  const int lane = tid & 63, wv = tid >> 6;

  const int nwg = gridDim.x;
  const int cpx = nwg >> 3;
  const int bid = blockIdx.x;
  const int l = (bid & 7) * cpx + (bid >> 3);
  const int nm = nwg / 192;
  const int m_i = l % nm;
  const int rest = l / nm;
  const int n_i = rest % 96;
  const int b = rest / 96;

  const int m0 = m_i << 7, n0 = n_i * 96;
  const unsigned short* Ag = Ap + (size_t)m0 * lda + aOff;
  const unsigned short* Bg = Bt + ((size_t)b * HW + n0) * rowK;

  const int wm = (wv >> 1) * 64, wn = (wv & 1) * 48;
  const int fr = lane & 15, hi = lane >> 4;
  const int nt = rowK >> 5;

  f32x4 acc[4][3];
#pragma unroll
  for (int i = 0; i < 4; ++i)
#pragma unroll
    for (int j = 0; j < 3; ++j) acc[i][j] = (f32x4){0.f, 0.f, 0.f, 0.f};

  stage_ab96(Ag, Bg, lda, rowK, 0,  &As[0][0], &Bs[0][0], wv, lane);
  stage_ab96(Ag, Bg, lda, rowK, 32, &As[1][0], &Bs[1][0], wv, lane);

  for (int t = 0; t < nt; ++t) {
    const int cur = t % 3;
    if (t + 2 < nt) {
      stage_ab96(Ag, Bg, lda, rowK, (t + 2) << 5, &As[(t + 2) % 3][0],
                 &Bs[(t + 2) % 3][0], wv, lane);
      if (wv < 2) asm volatile("s_waitcnt vmcnt(8)" ::: "memory");
      else        asm volatile("s_waitcnt vmcnt(6)" ::: "memory");
    } else if (t + 1 < nt) {
      if (wv < 2) asm volatile("s_waitcnt vmcnt(4)" ::: "memory");
      else        asm volatile("s_waitcnt vmcnt(3)" ::: "memory");
    } else {
      asm volatile("s_waitcnt vmcnt(0)" ::: "memory");
    }
    __builtin_amdgcn_s_barrier();
    __builtin_amdgcn_sched_barrier(0);
    bf16x8 a[4], bb[3];
#pragma unroll
    for (int i = 0; i < 4; ++i) {
      int row = wm + i * 16 + fr;
      a[i] = *(const bf16x8*)&As[cur][row * 32 + ((hi ^ ((row >> 1) & 3)) * 8)];
    }
#pragma unroll
    for (int j = 0; j < 3; ++j) {
      int row = wn + j * 16 + fr;
      bb[j] = *(const bf16x8*)&Bs[cur][row * 32 + ((hi ^ ((row >> 1) & 3)) * 8)];
    }
    __builtin_amdgcn_s_setprio(1);
#pragma unroll
    for (int i = 0; i < 4; ++i)
#pragma unroll
      for (int j = 0; j < 3; ++j)
        acc[i][j] = __builtin_amdgcn_mfma_f32_16x16x32_bf16(a[i], bb[j], acc[i][j], 0, 0, 0);
    __builtin_amdgcn_s_setprio(0);
    __builtin_amdgcn_s_barrier();
  }

  unsigned short* Yb = Yh + (size_t)b * FSTRIDE;
  const int orow = m0 + wm + hi * 4;
  const int ocol = n0 + wn + fr;
  float s_[4], q_[4];
#pragma unroll
  for (int i = 0; i < 4; ++i) { s_[i] = 0.f; q_[i] = 0.f; }
#pragma unroll
  for (int i = 0; i < 4; ++i) {
#pragma unroll
    for (int j = 0; j < 3; ++j) {
      unsigned short* p = Yb + (size_t)(orow + i * 16) * HW + ocol + j * 16;
#pragma unroll
      for (int q = 0; q < 4; ++q) {
        float v = acc[i][j][q];
        if (accum) v += bf2f(p[(size_t)q * HW]);
        p[(size_t)q * HW] = f2bf(v);
        s_[i] += v;
        q_[i] += v * v;
      }
    }
  }

  if (dogn) {
    const int redmax = (CperG == 16) ? 32 : 16;
#pragma unroll
    for (int i = 0; i < 4; ++i) {
      float s = s_[i], q = q_[i];
      for (int off = 1; off <= redmax; off <<= 1) {
        s += __shfl_xor(s, off);
        q += __shfl_xor(q, off);
      }
      int row0 = m0 + wm + i * 16 + ((CperG == 8) ? (lane >> 5) * 8 : 0);
      int g = row0 / CperG;
      bool writer = (CperG == 16) ? (lane == 0) : ((lane & 31) == 0);
      if (writer)
        gnp[(((size_t)(b * 32 + g)) * 96 + n_i) * 2 + (wv & 1)] = make_float2(s, q);
    }
  }
}

// ---------------- GN finalize from dcgemm partials (192 slots/group) -------
__global__ void k_gnfin2(const float2* __restrict__ gnp, float2* __restrict__ stat,
                         int CperG) {
  int t = threadIdx.x;  // 0..63 = b*32+g
  float s = 0.f, q = 0.f;
  for (int j = 0; j < 192; ++j) {
    float2 v = gnp[(size_t)t * 192 + j];
    s += v.x; q += v.y;
  }
  float n = (float)(CperG * HW);
  float m = s / n;
  float var = q / n - m * m;
  stat[t] = make_float2(m, rsqrtf(var + 1e-5f));
}

// ---------------- fallback GN stats from yh (3-chunk path only) ------------
__global__ void __launch_bounds__(256) k_gnstats1h(const unsigned short* __restrict__ yh,
                                                   float2* __restrict__ part, int CperG) {
  const int b = blockIdx.z, g = blockIdx.x, ch = blockIdx.y;
  const int n = CperG * HW;
  const int cs8 = (n >> 4) >> 3;
  const u16x8* p = (const u16x8*)(yh + (size_t)b * FSTRIDE + (size_t)g * n + (size_t)ch * (n >> 4));
  float s = 0.f, q = 0.f;
  for (int i = threadIdx.x; i < cs8; i += 256) {
    u16x8 v = p[i];
#pragma unroll
    for (int j = 0; j < 8; ++j) { float f = bf2f(v[j]); s += f; q += f * f; }
  }
  __shared__ float ss[256], qs[256];
  ss[threadIdx.x] = s; qs[threadIdx.x] = q;
  __syncthreads();
  for (int d = 128; d > 0; d >>= 1) {
    if (threadIdx.x < d) { ss[threadIdx.x] += ss[threadIdx.x + d]; qs[threadIdx.x] += qs[threadIdx.x + d]; }
    __syncthreads();
  }
  if (threadIdx.x == 0) part[((b << 5) + g) * 16 + ch] = make_float2(ss[0], qs[0]);
}

__global__ void k_gnfin(const float2* __restrict__ part, float2* __restrict__ stat,
                        int CperG) {
  int t = threadIdx.x;
  float s = 0.f, q = 0.f;
#pragma unroll
  for (int j = 0; j < 16; ++j) { float2 v = part[t * 16 + j]; s += v.x; q += v.y; }
  float n = (float)(CperG * HW);
  float m = s / n;
  float var = q / n - m * m;
  stat[t] = make_float2(m, rsqrtf(var + 1e-5f));
}

// ------- fused layer-4 GN-apply + cosine partials ----------
__global__ void __launch_bounds__(256) k_gncos(
    const unsigned short* __restrict__ yh, const float2* __restrict__ stat,
    const float* __restrict__ gamma, const float* __restrict__ beta,
    float* __restrict__ res, float4* __restrict__ cospart) {
  int px = blockIdx.x * 256 + threadIdx.x;
  int cc = blockIdx.y;
  float saa = 0.f, sbb = 0.f, sab = 0.f;
  for (int c = cc * 32; c < cc * 32 + 32; ++c) {
    float2 st0 = stat[c >> 3];
    float2 st1 = stat[32 + (c >> 3)];
    float ga = gamma[c], be = beta[c];
    float a = fmaxf((bf2f(yh[(size_t)c * HW + px]) - st0.x) * st0.y * ga + be, 0.f);
    float b = fmaxf((bf2f(yh[(size_t)FSTRIDE + (size_t)c * HW + px]) - st1.x) * st1.y * ga + be, 0.f);
    res[(size_t)c * HW + px] = a;
    res[(size_t)RSTRIDE + (size_t)c * HW + px] = b;
    saa += a * a; sbb += b * b; sab += a * b;
  }
  cospart[(size_t)cc * HW + px] = make_float4(saa, sbb, sab, 0.f);
}

__global__ void k_cos2(const float4* __restrict__ part, float* __restrict__ wpix) {
  int px = blockIdx.x * 256 + threadIdx.x;
  float saa = 0.f, sbb = 0.f, sab = 0.f;
#pragma unroll
  for (int cc = 0; cc < 8; ++cc) {
    float4 v = part[(size_t)cc * HW + px];
    saa += v.x; sbb += v.y; sab += v.z;
  }
  float na = sqrtf(saa), nb = sqrtf(sbb);
  float ttw = saa / fmaxf(na * na, 1e-8f);
  float tkw = sab / fmaxf(na * nb, 1e-8f);
  float m = fmaxf(ttw, tkw);
  float e0 = expf(ttw - m), e1 = expf(tkw - m);
  wpix[px] = e0 / (e0 + e1);
}

__global__ void k_combine(const float* __restrict__ res, const float* __restrict__ wpix,
                          float* __restrict__ out) {
  int i = blockIdx.x * 256 + threadIdx.x;
  int px = i % HW;
  float w0 = wpix[px];
  out[i] = w0 * res[i] + (1.f - w0) * res[(size_t)RSTRIDE + i];
}

extern "C" void kernel_launch(void* const* d_in, const int* in_sizes, int n_in,
                              void* d_out, int out_size, void* d_ws, size_t ws_size,
                              hipStream_t stream) {
  const float* datas = (const float*)d_in[0];
  const float* ow[4] = {(const float*)d_in[1], (const float*)d_in[6],
                        (const float*)d_in[11], (const float*)d_in[16]};
  const float* ob[4] = {(const float*)d_in[2], (const float*)d_in[7],
                        (const float*)d_in[12], (const float*)d_in[17]};
  const float* dw[4] = {(const float*)d_in[3], (const float*)d_in[8],
                        (const float*)d_in[13], (const float*)d_in[18]};
  const float* gg[4] = {(const float*)d_in[4], (const float*)d_in[9],
                        (const float*)d_in[14], (const float*)d_in[19]};
  const float* gb[4] = {(const float*)d_in[5], (const float*)d_in[10],
                        (const float*)d_in[15], (const float*)d_in[20]};

  // full-K layout needs ~247.8 MB (all-layer Ap/Wt hoisted); else 3-chunk.
  const int fullk = (ws_size >= 248500000ull) ? 1 : 0;
  const size_t sampN = fullk ? (2 * (size_t)HW * 4608) : (2 * (size_t)HW * 1536);

  float* ws = (float*)d_ws;
  unsigned short* yh = (unsigned short*)ws;               // 2*FSTRIDE bf16
  float* offp3 = ws + (2 * (size_t)FSTRIDE * 2) / 4;      // 2*3*PXP*32 fp32
  float4* tabw = (float4*)(offp3 + 2 * 3 * (size_t)PXP * 32);
  int4*   tabi = (int4*)(tabw + 2 * (size_t)TABSTRIDE);
  float* wpix = (float*)(tabi + 2 * (size_t)TABSTRIDE);   // HW
  float2* stat = (float2*)(wpix + HW);                    // 64
  float2* gnp  = stat + 64;                               // 2*32*96*2 float2
  float2* gnpart = gnp + 2 * 32 * 96 * 2;                 // 1024 (fallback)
  float4* cospart = (float4*)(gnpart + 1024);             // 8*HW
  float* endp = (float*)(cospart + 8 * (size_t)HW);
  size_t ofs = ((size_t)(endp - ws) + 3) & ~(size_t)3;
  unsigned short* samp = (unsigned short*)(ws + ofs);
  unsigned short* apAll = samp + sampN;                   // 7667712 us
  unsigned short* wtAll = apAll + (size_t)7667712;        // 589824 us
  unsigned short* ftp512 = wtAll + (size_t)589824;        // 2*FTPROWS*512
  unsigned short* ftp256 = fullk ? (samp + 2 * (size_t)HW * 2304)
                                 : (ftp512 + 2 * (size_t)FTPROWS * 512);
  float* res = (float*)(ftp256 + 2 * (size_t)FTPROWS * 256);

  dim3 blk(256);
  k_zero<<<dim3(2 * FTPROWS * 512 / 8 / 256), blk, 0, stream>>>(ftp512, 2u * FTPROWS * 512 / 8);
  k_prepA_all<<<dim3(29952), blk, 0, stream>>>(dw[0], dw[1], dw[2], dw[3], apAll);
  k_prepW_all<<<dim3(2304), blk, 0, stream>>>(ow[0], ow[1], ow[2], ow[3], wtAll);

  for (int lyr = 0; lyr < 4; ++lyr) {
    const int Cx = (lyr < 3) ? 512 : 256;
    const int M  = Cx;
    const int CperG = (lyr < 3) ? 16 : 8;
    const unsigned short* Ap = (lyr < 3) ? (apAll + (size_t)lyr * 2359296)
                                         : (apAll + (size_t)7077888);
    const unsigned short* Wt = wtAll + (size_t)lyr * 147456;
    if (lyr == 0) {
      k_mkftp_cat<<<dim3(144, 8, 2), blk, 0, stream>>>(datas + RSTRIDE, datas,
                                                       datas + RSTRIDE, ftp512, 512, 256);
    } else {
      k_mkftp_gn<<<dim3(144, 8, 2), blk, 0, stream>>>(yh, stat, gg[lyr - 1], gb[lyr - 1],
                                                      ftp512);
    }
    k_offmm<<<dim3(96, 3, 2), blk, 0, stream>>>(ftp512, Wt, offp3);
    k_table<<<dim3(36, 9, 2), blk, 0, stream>>>(offp3, ob[lyr], tabi, tabw);
    const unsigned short* sftp;
    if (lyr < 3) {
      sftp = ftp512;
    } else {
      k_zero<<<dim3(2 * FTPROWS * 256 / 8 / 256), blk, 0, stream>>>(ftp256, 2u * FTPROWS * 256 / 8);
      k_mkftp_cat<<<dim3(144, 4, 2), blk, 0, stream>>>(datas + RSTRIDE, datas,
                                                       datas, ftp256, 256, 256);
      sftp = ftp256;
    }
    const int nch = fullk ? 1 : 3;
    const int nk = 9 / nch;
    const int rowK = nk * Cx;
    const int yc = Cx / 64;
    for (int ch = 0; ch < nch; ++ch) {
      k_sample_t<<<dim3(144 * yc * 2 * nk), blk, 0, stream>>>(sftp, tabi, tabw, samp,
                                                              Cx, ch * nk, rowK, yc);
      k_dcgemm<<<dim3((M / 128) * 96 * 2), blk, 0, stream>>>(
          Ap, samp, yh, gnp, 9 * Cx, rowK, ch * rowK, ch > 0, CperG,
          fullk && (ch == nch - 1));
    }
    if (fullk) {
      k_gnfin2<<<dim3(1), dim3(64), 0, stream>>>(gnp, stat, CperG);
    } else {
      k_gnstats1h<<<dim3(32, 16, 2), blk, 0, stream>>>(yh, gnpart, CperG);
      k_gnfin<<<dim3(1), dim3(64), 0, stream>>>(gnpart, stat, CperG);
    }
  }

  // layer-4 fused GN-apply + cosine partials, then blend
  k_gncos<<<dim3(36, 8), blk, 0, stream>>>(yh, stat, gg[3], gb[3], res, cospart);
  k_cos2<<<dim3(36), blk, 0, stream>>>(cospart, wpix);
  k_combine<<<dim3(RSTRIDE / 256), blk, 0, stream>>>(res, wpix, (float*)d_out);
}

// Round 17
// 844.082 us; speedup vs baseline: 1.2553x; 1.0539x over previous
//
#include <hip/hip_runtime.h>
#include <math.h>

#define HW 9216
#define WIDTH 96
#define FSTRIDE (512*HW)          // 4718592
#define RSTRIDE (256*HW)          // 2359296
#define TABSTRIDE (9*HW)          // 82944
#define PXP 12544                 // 98 rows * 128
#define FTPROWS 12800             // 100 rows (guard + 98 + guard)

typedef __attribute__((ext_vector_type(8))) short bf16x8;
typedef __attribute__((ext_vector_type(4))) float f32x4;
typedef __attribute__((ext_vector_type(8))) unsigned short u16x8;

__device__ __forceinline__ unsigned short f2bf(float f) {
  unsigned int u = __float_as_uint(f);
  u += 0x7FFFu + ((u >> 16) & 1u);   // RNE
  return (unsigned short)(u >> 16);
}
__device__ __forceinline__ float bf2f(unsigned short s) {
  return __uint_as_float(((unsigned int)s) << 16);
}

#define GLDS(g, l) __builtin_amdgcn_global_load_lds( \
    (const __attribute__((address_space(1))) unsigned int*)(g), \
    (__attribute__((address_space(3))) unsigned int*)(l), 16, 0, 0)

// ---------------- zero helper ----------------
__global__ void k_zero(unsigned short* p, unsigned int n8) {
  unsigned int i = blockIdx.x * 256 + threadIdx.x;
  if (i < n8) ((u16x8*)p)[i] = (u16x8){0, 0, 0, 0, 0, 0, 0, 0};
}

// ---------------- ftp from concat sources: [b][pxp][C] bf16 ----------------
__global__ void __launch_bounds__(256) k_mkftp_cat(
    const float* __restrict__ lo0, const float* __restrict__ lo1,
    const float* __restrict__ hi, unsigned short* __restrict__ dst,
    int C, int CB) {
  const int b = blockIdx.z;
  const float* lo = b ? lo1 : lo0;
  unsigned short* d = dst + (size_t)b * FTPROWS * C + 128 * C;
  const int px0 = blockIdx.x * 64, c0 = blockIdx.y * 64;
  __shared__ float tile[64][65];
  const int t = threadIdx.x;
#pragma unroll
  for (int rep = 0; rep < 16; ++rep) {
    int idx = rep * 256 + t;
    int cl = idx >> 6, pl = idx & 63;
    int cg = c0 + cl;
    const float* s = (cg < CB) ? (lo + (size_t)cg * HW) : (hi + (size_t)(cg - CB) * HW);
    tile[cl][pl] = s[px0 + pl];
  }
  __syncthreads();
  const int pl = t >> 2, cu = (t & 3) * 16;
  const int px = px0 + pl;
  const int h = px / WIDTH, w = px - h * WIDTH;
  const size_t pxp = (size_t)(h + 1) * 128 + (w + 1);
  u16x8 o0, o1;
#pragma unroll
  for (int j = 0; j < 8; ++j) o0[j] = f2bf(tile[cu + j][pl]);
#pragma unroll
  for (int j = 0; j < 8; ++j) o1[j] = f2bf(tile[cu + 8 + j][pl]);
  unsigned short* p = d + pxp * C + c0 + cu;
  *(u16x8*)p = o0;
  *(u16x8*)(p + 8) = o1;
}

// ---------------- ftp from GN(yh bf16)+ReLU (C=512, CperG=16) --------------
__global__ void __launch_bounds__(256) k_mkftp_gn(
    const unsigned short* __restrict__ yh, const float2* __restrict__ stat,
    const float* __restrict__ gamma, const float* __restrict__ beta,
    unsigned short* __restrict__ dst) {
  const int C = 512;
  const int b = blockIdx.z;
  unsigned short* d = dst + (size_t)b * FTPROWS * C + 128 * C;
  const int px0 = blockIdx.x * 64, c0 = blockIdx.y * 64;
  __shared__ float tile[64][65];
  const int t = threadIdx.x;
#pragma unroll
  for (int rep = 0; rep < 16; ++rep) {
    int idx = rep * 256 + t;
    int cl = idx >> 6, pl = idx & 63;
    int cg = c0 + cl;
    float2 st = stat[b * 32 + (cg >> 4)];
    float v = bf2f(yh[(size_t)b * FSTRIDE + (size_t)cg * HW + px0 + pl]);
    v = (v - st.x) * st.y * gamma[cg] + beta[cg];
    tile[cl][pl] = fmaxf(v, 0.f);
  }
  __syncthreads();
  const int pl = t >> 2, cu = (t & 3) * 16;
  const int px = px0 + pl;
  const int h = px / WIDTH, w = px - h * WIDTH;
  const size_t pxp = (size_t)(h + 1) * 128 + (w + 1);
  u16x8 o0, o1;
#pragma unroll
  for (int j = 0; j < 8; ++j) o0[j] = f2bf(tile[cu + j][pl]);
#pragma unroll
  for (int j = 0; j < 8; ++j) o1[j] = f2bf(tile[cu + 8 + j][pl]);
  unsigned short* p = d + pxp * C + c0 + cu;
  *(u16x8*)p = o0;
  *(u16x8*)(p + 8) = o1;
}

// ------- offconv weights, ALL layers: Wt[lyr][k][oc(32 pad)][c] bf16 -------
__global__ void k_prepW_all(const float* __restrict__ ow0, const float* __restrict__ ow1,
                            const float* __restrict__ ow2, const float* __restrict__ ow3,
                            unsigned short* __restrict__ wt) {
  int i = blockIdx.x * 256 + threadIdx.x;      // < 4*9*32*512
  int lyr = i / 147456, r0 = i % 147456;
  const float* ow = (lyr == 0) ? ow0 : (lyr == 1) ? ow1 : (lyr == 2) ? ow2 : ow3;
  int k = r0 / (32 * 512), r = r0 - k * 32 * 512;
  int oc = r / 512, c = r - oc * 512;
  wt[i] = (oc < 18) ? f2bf(ow[((size_t)oc * 512 + c) * 9 + k]) : (unsigned short)0;
}

// ------- dcgemm weights, ALL layers: Ap[m][k*C+c] = dw[m][c][k] bf16 -------
__global__ void k_prepA_all(const float* __restrict__ dw0, const float* __restrict__ dw1,
                            const float* __restrict__ dw2, const float* __restrict__ dw3,
                            unsigned short* __restrict__ ap) {
  int i = blockIdx.x * 256 + threadIdx.x;      // < 7667712
  int lyr, o, C; size_t base;
  if (i < 7077888) { lyr = i / 2359296; o = i % 2359296; C = 512; base = (size_t)lyr * 2359296; }
  else             { lyr = 3; o = i - 7077888; C = 256; base = 7077888; }
  const float* dw = (lyr == 0) ? dw0 : (lyr == 1) ? dw1 : (lyr == 2) ? dw2 : dw3;
  int K = 9 * C;
  int m = o / K, r = o - m * K;
  int k = r / C, c = r - k * C;
  ap[base + o] = f2bf(dw[((size_t)m * C + c) * 9 + k]);
}

// ------ offset conv via MFMA, 2-deep pipeline, XCD-chunked 1D grid ---------
// nwg = 576; logical l: ks inner, pxp mid, b outer -> the 3 ks sharing one
// 128-row A panel co-reside on one XCD (24 panels x 128KB = 3MB < 4MB L2).
__global__ void __launch_bounds__(256) k_offmm(const unsigned short* __restrict__ ftp,
                                               const unsigned short* __restrict__ Wt,
                                               float* __restrict__ part) {
  const int C = 512;
  __shared__ unsigned short As[2][128 * 64];  // 2 x 16 KB
  __shared__ unsigned short Bs[2][32 * 64];   // 2 x 4 KB
  const int tid = threadIdx.x;
  const int lane = tid & 63, wv = tid >> 6;

  const int nwg = gridDim.x;          // 576
  const int cpx = nwg >> 3;
  const int bid = blockIdx.x;
  const int l = (bid & 7) * cpx + (bid >> 3);
  const int ks = l % 3;
  const int r = l / 3;
  const int pxi = r % 96;
  const int b = r / 96;
  const int pxp0 = 128 + pxi * 128;
  const unsigned short* fb = ftp + (size_t)b * FTPROWS * C + 128 * C;

  const int lr = lane >> 3;
  const int lu = lane & 7;
  const int fr = lane & 15, hi = lane >> 4;

  f32x4 acc[2][2];
#pragma unroll
  for (int i = 0; i < 2; ++i)
#pragma unroll
    for (int j = 0; j < 2; ++j) acc[i][j] = (f32x4){0.f, 0.f, 0.f, 0.f};

#define OFFMM_STAGE(S, BUF)                                                   \
  {                                                                           \
    const int k_ = ks * 3 + ((S) >> 3);                                       \
    const int dlt_ = (k_ / 3 - 1) * 128 + (k_ % 3 - 1);                       \
    const int c0_ = ((S) & 7) * 64;                                           \
    _Pragma("unroll")                                                         \
    for (int q = 0; q < 4; ++q) {                                             \
      int row = wv * 32 + q * 8 + lr;                                         \
      int su = lu ^ (row & 7);                                                \
      GLDS(fb + (size_t)(pxp0 + dlt_ + row) * C + c0_ + su * 8,               \
           (char*)&As[BUF][0] + (wv * 32 + q * 8) * 128);                     \
    }                                                                         \
    {                                                                         \
      int row = wv * 8 + lr;                                                  \
      int su = lu ^ (row & 7);                                                \
      GLDS(Wt + ((size_t)k_ * 32 + row) * C + c0_ + su * 8,                   \
           (char*)&Bs[BUF][0] + wv * 8 * 128);                                \
    }                                                                         \
  }

  OFFMM_STAGE(0, 0);
  for (int s = 0; s < 24; ++s) {
    const int cur = s & 1;
    if (s + 1 < 24) {
      OFFMM_STAGE(s + 1, cur ^ 1);
      asm volatile("s_waitcnt vmcnt(5)" ::: "memory");
    } else {
      asm volatile("s_waitcnt vmcnt(0)" ::: "memory");
    }
    __builtin_amdgcn_s_barrier();
#pragma unroll
    for (int kk = 0; kk < 2; ++kk) {
      bf16x8 a[2], bb[2];
#pragma unroll
      for (int i = 0; i < 2; ++i) {
        int row = wv * 32 + i * 16 + fr;
        a[i] = *(const bf16x8*)&As[cur][row * 64 + (((kk * 4 + hi) ^ (row & 7)) * 8)];
      }
#pragma unroll
      for (int j = 0; j < 2; ++j) {
        int row = j * 16 + fr;
        bb[j] = *(const bf16x8*)&Bs[cur][row * 64 + (((kk * 4 + hi) ^ (row & 7)) * 8)];
      }
#pragma unroll
      for (int i = 0; i < 2; ++i)
#pragma unroll
        for (int j = 0; j < 2; ++j)
          acc[i][j] = __builtin_amdgcn_mfma_f32_16x16x32_bf16(a[i], bb[j], acc[i][j], 0, 0, 0);
    }
    __builtin_amdgcn_s_barrier();
  }

  float* pb = part + ((size_t)(b * 3 + ks)) * PXP * 32;
#pragma unroll
  for (int i = 0; i < 2; ++i)
#pragma unroll
    for (int j = 0; j < 2; ++j) {
      int row0 = pxp0 + wv * 32 + i * 16 + hi * 4;
      int col = j * 16 + fr;
#pragma unroll
      for (int q = 0; q < 4; ++q)
        pb[(size_t)(row0 + q) * 32 + col] = acc[i][j][q];
    }
}

// ---------------- bilinear tables ----------------
__global__ void k_table(const float* __restrict__ part, const float* __restrict__ ob,
                        int4* __restrict__ tabi, float4* __restrict__ tabw) {
  int b = blockIdx.z, k = blockIdx.y;
  int px = blockIdx.x * 256 + threadIdx.x;
  int h = px / WIDTH, w = px - h * WIDTH;
  size_t pxp = (size_t)(h + 1) * 128 + (w + 1);
  const float* pb = part + (size_t)b * 3 * PXP * 32 + pxp * 32;
  float dy = ob[2 * k] + pb[2 * k] + pb[(size_t)PXP * 32 + 2 * k] + pb[2 * (size_t)PXP * 32 + 2 * k];
  float dx = ob[2 * k + 1] + pb[2 * k + 1] + pb[(size_t)PXP * 32 + 2 * k + 1] + pb[2 * (size_t)PXP * 32 + 2 * k + 1];
  float py = (float)(h - 1 + k / 3) + dy;
  float pxx = (float)(w - 1 + k % 3) + dx;
  float y0 = floorf(py), x0 = floorf(pxx);
  float ay = py - y0, ax = pxx - x0;
  float wy[2] = {1.f - ay, ay}, wx[2] = {1.f - ax, ax};
  int idx[4]; float wt[4];
#pragma unroll
  for (int t = 0; t < 4; ++t) {
    float oy = y0 + (float)(t >> 1);
    float ox = x0 + (float)(t & 1);
    bool valid = (oy >= 0.f) && (oy <= 95.f) && (ox >= 0.f) && (ox <= 95.f);
    int yi = (int)fminf(fmaxf(oy, 0.f), 95.f);
    int xi = (int)fminf(fmaxf(ox, 0.f), 95.f);
    idx[t] = (yi + 1) * 128 + (xi + 1);
    wt[t] = valid ? wy[t >> 1] * wx[t & 1] : 0.f;
  }
  size_t e = (size_t)b * TABSTRIDE + (size_t)k * HW + px;
  tabi[e] = make_int4(idx[0], idx[1], idx[2], idx[3]);
  tabw[e] = make_float4(wt[0], wt[1], wt[2], wt[3]);
}

// ---- sampled from ftp: R13 body, XCD-chunked 1D grid (R16-verified) -------
__global__ void __launch_bounds__(256) k_sample_t(
    const unsigned short* __restrict__ ftp,
    const int4* __restrict__ tabi, const float4* __restrict__ tabw,
    unsigned short* __restrict__ samp, int C, int kbase, int rowK, int yc) {
  const int nwg = gridDim.x;
  const int cpx = nwg >> 3;
  const int bid = blockIdx.x;
  const int l = (bid & 7) * cpx + (bid >> 3);
  const int ci = l % yc;
  const int r = l / yc;
  const int pxi = r % 144;
  const int zk = r / 144;
  const int b = zk & 1, kloc = zk >> 1;
  const int k = kbase + kloc;
  const int t = threadIdx.x;
  const int px = pxi * 64 + (t >> 2);
  const int c = ci * 64 + (t & 3) * 16;
  const unsigned short* fb = ftp + (size_t)b * FTPROWS * C + 128 * C;
  size_t e = (size_t)b * TABSTRIDE + (size_t)k * HW + px;
  int4 id = tabi[e];
  float4 wt = tabw[e];
  float acc[16];
#pragma unroll
  for (int j = 0; j < 16; ++j) acc[j] = 0.f;
  const int ids[4] = {id.x, id.y, id.z, id.w};
  const float wts[4] = {wt.x, wt.y, wt.z, wt.w};
#pragma unroll
  for (int s = 0; s < 4; ++s) {
    const unsigned short* p = fb + (size_t)ids[s] * C + c;
    u16x8 v0 = *(const u16x8*)p;
    u16x8 v1 = *(const u16x8*)(p + 8);
    float wgt = wts[s];
#pragma unroll
    for (int j = 0; j < 8; ++j) acc[j] += wgt * bf2f(v0[j]);
#pragma unroll
    for (int j = 0; j < 8; ++j) acc[8 + j] += wgt * bf2f(v1[j]);
  }
  u16x8 o0, o1;
#pragma unroll
  for (int j = 0; j < 8; ++j) o0[j] = f2bf(acc[j]);
#pragma unroll
  for (int j = 0; j < 8; ++j) o1[j] = f2bf(acc[8 + j]);
  unsigned short* dst = samp + ((size_t)b * HW + px) * rowK + kloc * C + c;
  *(u16x8*)dst = o0;
  *(u16x8*)(dst + 8) = o1;
}

// ---- staging 128x96 BK=32: A=8 units, B=6 units; w0,w1:2A+2B; w2,w3:2A+1B --
__device__ __forceinline__ void stage_ab96(const unsigned short* __restrict__ Ag,
                                           const unsigned short* __restrict__ Bg,
                                           int lda, int rowK, int kt,
                                           unsigned short* as_, unsigned short* bs_,
                                           int wv, int lane) {
  const int lr = lane >> 2;
  const int lu = lane & 3;
#pragma unroll
  for (int q = 0; q < 2; ++q) {
    int row = wv * 32 + q * 16 + lr;
    int su = lu ^ ((row >> 1) & 3);
    GLDS(Ag + (size_t)row * lda + kt + su * 8, (char*)as_ + (wv * 2 + q) * 1024);
  }
  const int nb = (wv < 2) ? 2 : 1;
  const int bu0 = (wv < 2) ? (2 * wv) : (wv + 2);
  for (int q = 0; q < nb; ++q) {
    int unit = bu0 + q;
    int row = unit * 16 + lr;
    int su = lu ^ ((row >> 1) & 3);
    GLDS(Bg + (size_t)row * rowK + kt + su * 8, (char*)bs_ + unit * 1024);
  }
}

// ---------------- bf16 MFMA GEMM: 128m x 96n, BK=32, 3-stage, bf16 Y -------
__global__ void __launch_bounds__(256) k_dcgemm(
    const unsigned short* __restrict__ Ap, const unsigned short* __restrict__ Bt,
    unsigned short* __restrict__ Yh, float2* __restrict__ gnp,
    int lda, int rowK, int aOff, int accum, int CperG, int dogn) {
  __shared__ unsigned short As[3][128 * 32];
  __shared__ unsigned short Bs[3][96 * 32];
  const int tid = threadIdx.x;
  const int lane = tid & 63, wv = tid >> 6;

  const int nwg = gridDim.x;
  const int cpx = nwg >> 3;
  const int bid = blockIdx.x;
  const int l = (bid & 7) * cpx + (bid >> 3);
  const int nm = nwg / 192;
  const int m_i = l % nm;
  const int rest = l / nm;
  const int n_i = rest % 96;
  const int b = rest / 96;

  const int m0 = m_i << 7, n0 = n_i * 96;
  const unsigned short* Ag = Ap + (size_t)m0 * lda + aOff;
  const unsigned short* Bg = Bt + ((size_t)b * HW + n0) * rowK;

  const int wm = (wv >> 1) * 64, wn = (wv & 1) * 48;
  const int fr = lane & 15, hi = lane >> 4;
  const int nt = rowK >> 5;

  f32x4 acc[4][3];
#pragma unroll
  for (int i = 0; i < 4; ++i)
#pragma unroll
    for (int j = 0; j < 3; ++j) acc[i][j] = (f32x4){0.f, 0.f, 0.f, 0.f};

  stage_ab96(Ag, Bg, lda, rowK, 0,  &As[0][0], &Bs[0][0], wv, lane);
  stage_ab96(Ag, Bg, lda, rowK, 32, &As[1][0], &Bs[1][0], wv, lane);

  for (int t = 0; t < nt; ++t) {
    const int cur = t % 3;
    if (t + 2 < nt) {
      stage_ab96(Ag, Bg, lda, rowK, (t + 2) << 5, &As[(t + 2) % 3][0],
                 &Bs[(t + 2) % 3][0], wv, lane);
      if (wv < 2) asm volatile("s_waitcnt vmcnt(8)" ::: "memory");
      else        asm volatile("s_waitcnt vmcnt(6)" ::: "memory");
    } else if (t + 1 < nt) {
      if (wv < 2) asm volatile("s_waitcnt vmcnt(4)" ::: "memory");
      else        asm volatile("s_waitcnt vmcnt(3)" ::: "memory");
    } else {
      asm volatile("s_waitcnt vmcnt(0)" ::: "memory");
    }
    __builtin_amdgcn_s_barrier();
    __builtin_amdgcn_sched_barrier(0);
    bf16x8 a[4], bb[3];
#pragma unroll
    for (int i = 0; i < 4; ++i) {
      int row = wm + i * 16 + fr;
      a[i] = *(const bf16x8*)&As[cur][row * 32 + ((hi ^ ((row >> 1) & 3)) * 8)];
    }
#pragma unroll
    for (int j = 0; j < 3; ++j) {
      int row = wn + j * 16 + fr;
      bb[j] = *(const bf16x8*)&Bs[cur][row * 32 + ((hi ^ ((row >> 1) & 3)) * 8)];
    }
    __builtin_amdgcn_s_setprio(1);
#pragma unroll
    for (int i = 0; i < 4; ++i)
#pragma unroll
      for (int j = 0; j < 3; ++j)
        acc[i][j] = __builtin_amdgcn_mfma_f32_16x16x32_bf16(a[i], bb[j], acc[i][j], 0, 0, 0);
    __builtin_amdgcn_s_setprio(0);
    __builtin_amdgcn_s_barrier();
  }

  unsigned short* Yb = Yh + (size_t)b * FSTRIDE;
  const int orow = m0 + wm + hi * 4;
  const int ocol = n0 + wn + fr;
  float s_[4], q_[4];
#pragma unroll
  for (int i = 0; i < 4; ++i) { s_[i] = 0.f; q_[i] = 0.f; }
#pragma unroll
  for (int i = 0; i < 4; ++i) {
#pragma unroll
    for (int j = 0; j < 3; ++j) {
      unsigned short* p = Yb + (size_t)(orow + i * 16) * HW + ocol + j * 16;
#pragma unroll
      for (int q = 0; q < 4; ++q) {
        float v = acc[i][j][q];
        if (accum) v += bf2f(p[(size_t)q * HW]);
        p[(size_t)q * HW] = f2bf(v);
        s_[i] += v;
        q_[i] += v * v;
      }
    }
  }

  if (dogn) {
    const int redmax = (CperG == 16) ? 32 : 16;
#pragma unroll
    for (int i = 0; i < 4; ++i) {
      float s = s_[i], q = q_[i];
      for (int off = 1; off <= redmax; off <<= 1) {
        s += __shfl_xor(s, off);
        q += __shfl_xor(q, off);
      }
      int row0 = m0 + wm + i * 16 + ((CperG == 8) ? (lane >> 5) * 8 : 0);
      int g = row0 / CperG;
      bool writer = (CperG == 16) ? (lane == 0) : ((lane & 31) == 0);
      if (writer)
        gnp[(((size_t)(b * 32 + g)) * 96 + n_i) * 2 + (wv & 1)] = make_float2(s, q);
    }
  }
}

// ---------------- GN finalize from dcgemm partials (192 slots/group) -------
__global__ void k_gnfin2(const float2* __restrict__ gnp, float2* __restrict__ stat,
                         int CperG) {
  int t = threadIdx.x;  // 0..63 = b*32+g
  float s = 0.f, q = 0.f;
  for (int j = 0; j < 192; ++j) {
    float2 v = gnp[(size_t)t * 192 + j];
    s += v.x; q += v.y;
  }
  float n = (float)(CperG * HW);
  float m = s / n;
  float var = q / n - m * m;
  stat[t] = make_float2(m, rsqrtf(var + 1e-5f));
}

// ---------------- fallback GN stats from yh (3-chunk path only) ------------
__global__ void __launch_bounds__(256) k_gnstats1h(const unsigned short* __restrict__ yh,
                                                   float2* __restrict__ part, int CperG) {
  const int b = blockIdx.z, g = blockIdx.x, ch = blockIdx.y;
  const int n = CperG * HW;
  const int cs8 = (n >> 4) >> 3;
  const u16x8* p = (const u16x8*)(yh + (size_t)b * FSTRIDE + (size_t)g * n + (size_t)ch * (n >> 4));
  float s = 0.f, q = 0.f;
  for (int i = threadIdx.x; i < cs8; i += 256) {
    u16x8 v = p[i];
#pragma unroll
    for (int j = 0; j < 8; ++j) { float f = bf2f(v[j]); s += f; q += f * f; }
  }
  __shared__ float ss[256], qs[256];
  ss[threadIdx.x] = s; qs[threadIdx.x] = q;
  __syncthreads();
  for (int d = 128; d > 0; d >>= 1) {
    if (threadIdx.x < d) { ss[threadIdx.x] += ss[threadIdx.x + d]; qs[threadIdx.x] += qs[threadIdx.x + d]; }
    __syncthreads();
  }
  if (threadIdx.x == 0) part[((b << 5) + g) * 16 + ch] = make_float2(ss[0], qs[0]);
}

__global__ void k_gnfin(const float2* __restrict__ part, float2* __restrict__ stat,
                        int CperG) {
  int t = threadIdx.x;
  float s = 0.f, q = 0.f;
#pragma unroll
  for (int j = 0; j < 16; ++j) { float2 v = part[t * 16 + j]; s += v.x; q += v.y; }
  float n = (float)(CperG * HW);
  float m = s / n;
  float var = q / n - m * m;
  stat[t] = make_float2(m, rsqrtf(var + 1e-5f));
}

// ------- fused layer-4 GN-apply + cosine partials ----------
__global__ void __launch_bounds__(256) k_gncos(
    const unsigned short* __restrict__ yh, const float2* __restrict__ stat,
    const float* __restrict__ gamma, const float* __restrict__ beta,
    float* __restrict__ res, float4* __restrict__ cospart) {
  int px = blockIdx.x * 256 + threadIdx.x;
  int cc = blockIdx.y;
  float saa = 0.f, sbb = 0.f, sab = 0.f;
  for (int c = cc * 32; c < cc * 32 + 32; ++c) {
    float2 st0 = stat[c >> 3];
    float2 st1 = stat[32 + (c >> 3)];
    float ga = gamma[c], be = beta[c];
    float a = fmaxf((bf2f(yh[(size_t)c * HW + px]) - st0.x) * st0.y * ga + be, 0.f);
    float b = fmaxf((bf2f(yh[(size_t)FSTRIDE + (size_t)c * HW + px]) - st1.x) * st1.y * ga + be, 0.f);
    res[(size_t)c * HW + px] = a;
    res[(size_t)RSTRIDE + (size_t)c * HW + px] = b;
    saa += a * a; sbb += b * b; sab += a * b;
  }
  cospart[(size_t)cc * HW + px] = make_float4(saa, sbb, sab, 0.f);
}

__global__ void k_cos2(const float4* __restrict__ part, float* __restrict__ wpix) {
  int px = blockIdx.x * 256 + threadIdx.x;
  float saa = 0.f, sbb = 0.f, sab = 0.f;
#pragma unroll
  for (int cc = 0; cc < 8; ++cc) {
    float4 v = part[(size_t)cc * HW + px];
    saa += v.x; sbb += v.y; sab += v.z;
  }
  float na = sqrtf(saa), nb = sqrtf(sbb);
  float ttw = saa / fmaxf(na * na, 1e-8f);
  float tkw = sab / fmaxf(na * nb, 1e-8f);
  float m = fmaxf(ttw, tkw);
  float e0 = expf(ttw - m), e1 = expf(tkw - m);
  wpix[px] = e0 / (e0 + e1);
}

__global__ void k_combine(const float* __restrict__ res, const float* __restrict__ wpix,
                          float* __restrict__ out) {
  int i = blockIdx.x * 256 + threadIdx.x;
  int px = i % HW;
  float w0 = wpix[px];
  out[i] = w0 * res[i] + (1.f - w0) * res[(size_t)RSTRIDE + i];
}

extern "C" void kernel_launch(void* const* d_in, const int* in_sizes, int n_in,
                              void* d_out, int out_size, void* d_ws, size_t ws_size,
                              hipStream_t stream) {
  const float* datas = (const float*)d_in[0];
  const float* ow[4] = {(const float*)d_in[1], (const float*)d_in[6],
                        (const float*)d_in[11], (const float*)d_in[16]};
  const float* ob[4] = {(const float*)d_in[2], (const float*)d_in[7],
                        (const float*)d_in[12], (const float*)d_in[17]};
  const float* dw[4] = {(const float*)d_in[3], (const float*)d_in[8],
                        (const float*)d_in[13], (const float*)d_in[18]};
  const float* gg[4] = {(const float*)d_in[4], (const float*)d_in[9],
                        (const float*)d_in[14], (const float*)d_in[19]};
  const float* gb[4] = {(const float*)d_in[5], (const float*)d_in[10],
                        (const float*)d_in[15], (const float*)d_in[20]};

  // full-K layout needs ~247.8 MB (all-layer Ap/Wt hoisted); else 3-chunk.
  const int fullk = (ws_size >= 248500000ull) ? 1 : 0;
  const size_t sampN = fullk ? (2 * (size_t)HW * 4608) : (2 * (size_t)HW * 1536);

  float* ws = (float*)d_ws;
  unsigned short* yh = (unsigned short*)ws;               // 2*FSTRIDE bf16
  float* offp3 = ws + (2 * (size_t)FSTRIDE * 2) / 4;      // 2*3*PXP*32 fp32
  float4* tabw = (float4*)(offp3 + 2 * 3 * (size_t)PXP * 32);
  int4*   tabi = (int4*)(tabw + 2 * (size_t)TABSTRIDE);
  float* wpix = (float*)(tabi + 2 * (size_t)TABSTRIDE);   // HW
  float2* stat = (float2*)(wpix + HW);                    // 64
  float2* gnp  = stat + 64;                               // 2*32*96*2 float2
  float2* gnpart = gnp + 2 * 32 * 96 * 2;                 // 1024 (fallback)
  float4* cospart = (float4*)(gnpart + 1024);             // 8*HW
  float* endp = (float*)(cospart + 8 * (size_t)HW);
  size_t ofs = ((size_t)(endp - ws) + 3) & ~(size_t)3;
  unsigned short* samp = (unsigned short*)(ws + ofs);
  unsigned short* apAll = samp + sampN;                   // 7667712 us
  unsigned short* wtAll = apAll + (size_t)7667712;        // 589824 us
  unsigned short* ftp512 = wtAll + (size_t)589824;        // 2*FTPROWS*512
  unsigned short* ftp256 = fullk ? (samp + 2 * (size_t)HW * 2304)
                                 : (ftp512 + 2 * (size_t)FTPROWS * 512);
  float* res = (float*)(ftp256 + 2 * (size_t)FTPROWS * 256);

  dim3 blk(256);
  k_zero<<<dim3(2 * FTPROWS * 512 / 8 / 256), blk, 0, stream>>>(ftp512, 2u * FTPROWS * 512 / 8);
  k_prepA_all<<<dim3(29952), blk, 0, stream>>>(dw[0], dw[1], dw[2], dw[3], apAll);
  k_prepW_all<<<dim3(2304), blk, 0, stream>>>(ow[0], ow[1], ow[2], ow[3], wtAll);

  for (int lyr = 0; lyr < 4; ++lyr) {
    const int Cx = (lyr < 3) ? 512 : 256;
    const int M  = Cx;
    const int CperG = (lyr < 3) ? 16 : 8;
    const unsigned short* Ap = (lyr < 3) ? (apAll + (size_t)lyr * 2359296)
                                         : (apAll + (size_t)7077888);
    const unsigned short* Wt = wtAll + (size_t)lyr * 147456;
    if (lyr == 0) {
      k_mkftp_cat<<<dim3(144, 8, 2), blk, 0, stream>>>(datas + RSTRIDE, datas,
                                                       datas + RSTRIDE, ftp512, 512, 256);
    } else {
      k_mkftp_gn<<<dim3(144, 8, 2), blk, 0, stream>>>(yh, stat, gg[lyr - 1], gb[lyr - 1],
                                                      ftp512);
    }
    k_offmm<<<dim3(576), blk, 0, stream>>>(ftp512, Wt, offp3);
    k_table<<<dim3(36, 9, 2), blk, 0, stream>>>(offp3, ob[lyr], tabi, tabw);
    const unsigned short* sftp;
    if (lyr < 3) {
      sftp = ftp512;
    } else {
      k_zero<<<dim3(2 * FTPROWS * 256 / 8 / 256), blk, 0, stream>>>(ftp256, 2u * FTPROWS * 256 / 8);
      k_mkftp_cat<<<dim3(144, 4, 2), blk, 0, stream>>>(datas + RSTRIDE, datas,
                                                       datas, ftp256, 256, 256);
      sftp = ftp256;
    }
    const int nch = fullk ? 1 : 3;
    const int nk = 9 / nch;
    const int rowK = nk * Cx;
    const int yc = Cx / 64;
    for (int ch = 0; ch < nch; ++ch) {
      k_sample_t<<<dim3(144 * yc * 2 * nk), blk, 0, stream>>>(sftp, tabi, tabw, samp,
                                                              Cx, ch * nk, rowK, yc);
      k_dcgemm<<<dim3((M / 128) * 96 * 2), blk, 0, stream>>>(
          Ap, samp, yh, gnp, 9 * Cx, rowK, ch * rowK, ch > 0, CperG,
          fullk && (ch == nch - 1));
    }
    if (fullk) {
      k_gnfin2<<<dim3(1), dim3(64), 0, stream>>>(gnp, stat, CperG);
    } else {
      k_gnstats1h<<<dim3(32, 16, 2), blk, 0, stream>>>(yh, gnpart, CperG);
      k_gnfin<<<dim3(1), dim3(64), 0, stream>>>(gnpart, stat, CperG);
    }
  }

  // layer-4 fused GN-apply + cosine partials, then blend
  k_gncos<<<dim3(36, 8), blk, 0, stream>>>(yh, stat, gg[3], gb[3], res, cospart);
  k_cos2<<<dim3(36), blk, 0, stream>>>(cospart, wpix);
  k_combine<<<dim3(RSTRIDE / 256), blk, 0, stream>>>(res, wpix, (float*)d_out);
}

// Round 18
// 832.585 us; speedup vs baseline: 1.2726x; 1.0138x over previous
//
#include <hip/hip_runtime.h>
#include <math.h>

#define HW 9216
#define WIDTH 96
#define FSTRIDE (512*HW)          // 4718592
#define RSTRIDE (256*HW)          // 2359296
#define TABSTRIDE (9*HW)          // 82944
#define PXP 12544                 // 98 rows * 128
#define FTPROWS 12800             // 100 rows (guard + 98 + guard)

typedef __attribute__((ext_vector_type(8))) short bf16x8;
typedef __attribute__((ext_vector_type(4))) float f32x4;
typedef __attribute__((ext_vector_type(8))) unsigned short u16x8;

__device__ __forceinline__ unsigned short f2bf(float f) {
  unsigned int u = __float_as_uint(f);
  u += 0x7FFFu + ((u >> 16) & 1u);   // RNE
  return (unsigned short)(u >> 16);
}
__device__ __forceinline__ float bf2f(unsigned short s) {
  return __uint_as_float(((unsigned int)s) << 16);
}

#define GLDS(g, l) __builtin_amdgcn_global_load_lds( \
    (const __attribute__((address_space(1))) unsigned int*)(g), \
    (__attribute__((address_space(3))) unsigned int*)(l), 16, 0, 0)

// ---------------- zero helper ----------------
__global__ void k_zero(unsigned short* p, unsigned int n8) {
  unsigned int i = blockIdx.x * 256 + threadIdx.x;
  if (i < n8) ((u16x8*)p)[i] = (u16x8){0, 0, 0, 0, 0, 0, 0, 0};
}

// ---------------- ftp from concat sources: [b][pxp][C] bf16 ----------------
__global__ void __launch_bounds__(256) k_mkftp_cat(
    const float* __restrict__ lo0, const float* __restrict__ lo1,
    const float* __restrict__ hi, unsigned short* __restrict__ dst,
    int C, int CB) {
  const int b = blockIdx.z;
  const float* lo = b ? lo1 : lo0;
  unsigned short* d = dst + (size_t)b * FTPROWS * C + 128 * C;
  const int px0 = blockIdx.x * 64, c0 = blockIdx.y * 64;
  __shared__ float tile[64][65];
  const int t = threadIdx.x;
#pragma unroll
  for (int rep = 0; rep < 16; ++rep) {
    int idx = rep * 256 + t;
    int cl = idx >> 6, pl = idx & 63;
    int cg = c0 + cl;
    const float* s = (cg < CB) ? (lo + (size_t)cg * HW) : (hi + (size_t)(cg - CB) * HW);
    tile[cl][pl] = s[px0 + pl];
  }
  __syncthreads();
  const int pl = t >> 2, cu = (t & 3) * 16;
  const int px = px0 + pl;
  const int h = px / WIDTH, w = px - h * WIDTH;
  const size_t pxp = (size_t)(h + 1) * 128 + (w + 1);
  u16x8 o0, o1;
#pragma unroll
  for (int j = 0; j < 8; ++j) o0[j] = f2bf(tile[cu + j][pl]);
#pragma unroll
  for (int j = 0; j < 8; ++j) o1[j] = f2bf(tile[cu + 8 + j][pl]);
  unsigned short* p = d + pxp * C + c0 + cu;
  *(u16x8*)p = o0;
  *(u16x8*)(p + 8) = o1;
}

// ---------------- ftp from GN(yh bf16)+ReLU (C=512, CperG=16) --------------
__global__ void __launch_bounds__(256) k_mkftp_gn(
    const unsigned short* __restrict__ yh, const float2* __restrict__ stat,
    const float* __restrict__ gamma, const float* __restrict__ beta,
    unsigned short* __restrict__ dst) {
  const int C = 512;
  const int b = blockIdx.z;
  unsigned short* d = dst + (size_t)b * FTPROWS * C + 128 * C;
  const int px0 = blockIdx.x * 64, c0 = blockIdx.y * 64;
  __shared__ float tile[64][65];
  const int t = threadIdx.x;
#pragma unroll
  for (int rep = 0; rep < 16; ++rep) {
    int idx = rep * 256 + t;
    int cl = idx >> 6, pl = idx & 63;
    int cg = c0 + cl;
    float2 st = stat[b * 32 + (cg >> 4)];
    float v = bf2f(yh[(size_t)b * FSTRIDE + (size_t)cg * HW + px0 + pl]);
    v = (v - st.x) * st.y * gamma[cg] + beta[cg];
    tile[cl][pl] = fmaxf(v, 0.f);
  }
  __syncthreads();
  const int pl = t >> 2, cu = (t & 3) * 16;
  const int px = px0 + pl;
  const int h = px / WIDTH, w = px - h * WIDTH;
  const size_t pxp = (size_t)(h + 1) * 128 + (w + 1);
  u16x8 o0, o1;
#pragma unroll
  for (int j = 0; j < 8; ++j) o0[j] = f2bf(tile[cu + j][pl]);
#pragma unroll
  for (int j = 0; j < 8; ++j) o1[j] = f2bf(tile[cu + 8 + j][pl]);
  unsigned short* p = d + pxp * C + c0 + cu;
  *(u16x8*)p = o0;
  *(u16x8*)(p + 8) = o1;
}

// ------- offconv weights, ALL layers: Wt[lyr][k][oc(32 pad)][c] bf16 -------
__global__ void k_prepW_all(const float* __restrict__ ow0, const float* __restrict__ ow1,
                            const float* __restrict__ ow2, const float* __restrict__ ow3,
                            unsigned short* __restrict__ wt) {
  int i = blockIdx.x * 256 + threadIdx.x;      // < 4*9*32*512
  int lyr = i / 147456, r0 = i % 147456;
  const float* ow = (lyr == 0) ? ow0 : (lyr == 1) ? ow1 : (lyr == 2) ? ow2 : ow3;
  int k = r0 / (32 * 512), r = r0 - k * 32 * 512;
  int oc = r / 512, c = r - oc * 512;
  wt[i] = (oc < 18) ? f2bf(ow[((size_t)oc * 512 + c) * 9 + k]) : (unsigned short)0;
}

// ------- dcgemm weights, ALL layers: Ap[m][k*C+c] = dw[m][c][k] bf16 -------
__global__ void k_prepA_all(const float* __restrict__ dw0, const float* __restrict__ dw1,
                            const float* __restrict__ dw2, const float* __restrict__ dw3,
                            unsigned short* __restrict__ ap) {
  int i = blockIdx.x * 256 + threadIdx.x;      // < 7667712
  int lyr, o, C; size_t base;
  if (i < 7077888) { lyr = i / 2359296; o = i % 2359296; C = 512; base = (size_t)lyr * 2359296; }
  else             { lyr = 3; o = i - 7077888; C = 256; base = 7077888; }
  const float* dw = (lyr == 0) ? dw0 : (lyr == 1) ? dw1 : (lyr == 2) ? dw2 : dw3;
  int K = 9 * C;
  int m = o / K, r = o - m * K;
  int k = r / C, c = r - k * C;
  ap[base + o] = f2bf(dw[((size_t)m * C + c) * 9 + k]);
}

// ------ offset conv via MFMA, 2-deep pipeline, XCD-chunked 1D grid ---------
__global__ void __launch_bounds__(256) k_offmm(const unsigned short* __restrict__ ftp,
                                               const unsigned short* __restrict__ Wt,
                                               float* __restrict__ part) {
  const int C = 512;
  __shared__ unsigned short As[2][128 * 64];  // 2 x 16 KB
  __shared__ unsigned short Bs[2][32 * 64];   // 2 x 4 KB
  const int tid = threadIdx.x;
  const int lane = tid & 63, wv = tid >> 6;

  const int nwg = gridDim.x;          // 576
  const int cpx = nwg >> 3;
  const int bid = blockIdx.x;
  const int l = (bid & 7) * cpx + (bid >> 3);
  const int ks = l % 3;
  const int r = l / 3;
  const int pxi = r % 96;
  const int b = r / 96;
  const int pxp0 = 128 + pxi * 128;
  const unsigned short* fb = ftp + (size_t)b * FTPROWS * C + 128 * C;

  const int lr = lane >> 3;
  const int lu = lane & 7;
  const int fr = lane & 15, hi = lane >> 4;

  f32x4 acc[2][2];
#pragma unroll
  for (int i = 0; i < 2; ++i)
#pragma unroll
    for (int j = 0; j < 2; ++j) acc[i][j] = (f32x4){0.f, 0.f, 0.f, 0.f};

#define OFFMM_STAGE(S, BUF)                                                   \
  {                                                                           \
    const int k_ = ks * 3 + ((S) >> 3);                                       \
    const int dlt_ = (k_ / 3 - 1) * 128 + (k_ % 3 - 1);                       \
    const int c0_ = ((S) & 7) * 64;                                           \
    _Pragma("unroll")                                                         \
    for (int q = 0; q < 4; ++q) {                                             \
      int row = wv * 32 + q * 8 + lr;                                         \
      int su = lu ^ (row & 7);                                                \
      GLDS(fb + (size_t)(pxp0 + dlt_ + row) * C + c0_ + su * 8,               \
           (char*)&As[BUF][0] + (wv * 32 + q * 8) * 128);                     \
    }                                                                         \
    {                                                                         \
      int row = wv * 8 + lr;                                                  \
      int su = lu ^ (row & 7);                                                \
      GLDS(Wt + ((size_t)k_ * 32 + row) * C + c0_ + su * 8,                   \
           (char*)&Bs[BUF][0] + wv * 8 * 128);                                \
    }                                                                         \
  }

  OFFMM_STAGE(0, 0);
  for (int s = 0; s < 24; ++s) {
    const int cur = s & 1;
    if (s + 1 < 24) {
      OFFMM_STAGE(s + 1, cur ^ 1);
      asm volatile("s_waitcnt vmcnt(5)" ::: "memory");
    } else {
      asm volatile("s_waitcnt vmcnt(0)" ::: "memory");
    }
    __builtin_amdgcn_s_barrier();
#pragma unroll
    for (int kk = 0; kk < 2; ++kk) {
      bf16x8 a[2], bb[2];
#pragma unroll
      for (int i = 0; i < 2; ++i) {
        int row = wv * 32 + i * 16 + fr;
        a[i] = *(const bf16x8*)&As[cur][row * 64 + (((kk * 4 + hi) ^ (row & 7)) * 8)];
      }
#pragma unroll
      for (int j = 0; j < 2; ++j) {
        int row = j * 16 + fr;
        bb[j] = *(const bf16x8*)&Bs[cur][row * 64 + (((kk * 4 + hi) ^ (row & 7)) * 8)];
      }
#pragma unroll
      for (int i = 0; i < 2; ++i)
#pragma unroll
        for (int j = 0; j < 2; ++j)
          acc[i][j] = __builtin_amdgcn_mfma_f32_16x16x32_bf16(a[i], bb[j], acc[i][j], 0, 0, 0);
    }
    __builtin_amdgcn_s_barrier();
  }

  float* pb = part + ((size_t)(b * 3 + ks)) * PXP * 32;
#pragma unroll
  for (int i = 0; i < 2; ++i)
#pragma unroll
    for (int j = 0; j < 2; ++j) {
      int row0 = pxp0 + wv * 32 + i * 16 + hi * 4;
      int col = j * 16 + fr;
#pragma unroll
      for (int q = 0; q < 4; ++q)
        pb[(size_t)(row0 + q) * 32 + col] = acc[i][j][q];
    }
}

// ---------------- bilinear tables ----------------
__global__ void k_table(const float* __restrict__ part, const float* __restrict__ ob,
                        int4* __restrict__ tabi, float4* __restrict__ tabw) {
  int b = blockIdx.z, k = blockIdx.y;
  int px = blockIdx.x * 256 + threadIdx.x;
  int h = px / WIDTH, w = px - h * WIDTH;
  size_t pxp = (size_t)(h + 1) * 128 + (w + 1);
  const float* pb = part + (size_t)b * 3 * PXP * 32 + pxp * 32;
  float dy = ob[2 * k] + pb[2 * k] + pb[(size_t)PXP * 32 + 2 * k] + pb[2 * (size_t)PXP * 32 + 2 * k];
  float dx = ob[2 * k + 1] + pb[2 * k + 1] + pb[(size_t)PXP * 32 + 2 * k + 1] + pb[2 * (size_t)PXP * 32 + 2 * k + 1];
  float py = (float)(h - 1 + k / 3) + dy;
  float pxx = (float)(w - 1 + k % 3) + dx;
  float y0 = floorf(py), x0 = floorf(pxx);
  float ay = py - y0, ax = pxx - x0;
  float wy[2] = {1.f - ay, ay}, wx[2] = {1.f - ax, ax};
  int idx[4]; float wt[4];
#pragma unroll
  for (int t = 0; t < 4; ++t) {
    float oy = y0 + (float)(t >> 1);
    float ox = x0 + (float)(t & 1);
    bool valid = (oy >= 0.f) && (oy <= 95.f) && (ox >= 0.f) && (ox <= 95.f);
    int yi = (int)fminf(fmaxf(oy, 0.f), 95.f);
    int xi = (int)fminf(fmaxf(ox, 0.f), 95.f);
    idx[t] = (yi + 1) * 128 + (xi + 1);
    wt[t] = valid ? wy[t >> 1] * wx[t & 1] : 0.f;
  }
  size_t e = (size_t)b * TABSTRIDE + (size_t)k * HW + px;
  tabi[e] = make_int4(idx[0], idx[1], idx[2], idx[3]);
  tabw[e] = make_float4(wt[0], wt[1], wt[2], wt[3]);
}

// ---- sampled from ftp: R13 body, XCD-chunked 1D grid (R16-verified) -------
__global__ void __launch_bounds__(256) k_sample_t(
    const unsigned short* __restrict__ ftp,
    const int4* __restrict__ tabi, const float4* __restrict__ tabw,
    unsigned short* __restrict__ samp, int C, int kbase, int rowK, int yc) {
  const int nwg = gridDim.x;
  const int cpx = nwg >> 3;
  const int bid = blockIdx.x;
  const int l = (bid & 7) * cpx + (bid >> 3);
  const int ci = l % yc;
  const int r = l / yc;
  const int pxi = r % 144;
  const int zk = r / 144;
  const int b = zk & 1, kloc = zk >> 1;
  const int k = kbase + kloc;
  const int t = threadIdx.x;
  const int px = pxi * 64 + (t >> 2);
  const int c = ci * 64 + (t & 3) * 16;
  const unsigned short* fb = ftp + (size_t)b * FTPROWS * C + 128 * C;
  size_t e = (size_t)b * TABSTRIDE + (size_t)k * HW + px;
  int4 id = tabi[e];
  float4 wt = tabw[e];
  float acc[16];
#pragma unroll
  for (int j = 0; j < 16; ++j) acc[j] = 0.f;
  const int ids[4] = {id.x, id.y, id.z, id.w};
  const float wts[4] = {wt.x, wt.y, wt.z, wt.w};
#pragma unroll
  for (int s = 0; s < 4; ++s) {
    const unsigned short* p = fb + (size_t)ids[s] * C + c;
    u16x8 v0 = *(const u16x8*)p;
    u16x8 v1 = *(const u16x8*)(p + 8);
    float wgt = wts[s];
#pragma unroll
    for (int j = 0; j < 8; ++j) acc[j] += wgt * bf2f(v0[j]);
#pragma unroll
    for (int j = 0; j < 8; ++j) acc[8 + j] += wgt * bf2f(v1[j]);
  }
  u16x8 o0, o1;
#pragma unroll
  for (int j = 0; j < 8; ++j) o0[j] = f2bf(acc[j]);
#pragma unroll
  for (int j = 0; j < 8; ++j) o1[j] = f2bf(acc[8 + j]);
  unsigned short* dst = samp + ((size_t)b * HW + px) * rowK + kloc * C + c;
  *(u16x8*)dst = o0;
  *(u16x8*)(dst + 8) = o1;
}

// ---- staging 128x96 BK=32: A=8 units, B=6 units; w0,w1:2A+2B; w2,w3:2A+1B --
__device__ __forceinline__ void stage_ab96(const unsigned short* __restrict__ Ag,
                                           const unsigned short* __restrict__ Bg,
                                           int lda, int rowK, int kt,
                                           unsigned short* as_, unsigned short* bs_,
                                           int wv, int lane) {
  const int lr = lane >> 2;
  const int lu = lane & 3;
#pragma unroll
  for (int q = 0; q < 2; ++q) {
    int row = wv * 32 + q * 16 + lr;
    int su = lu ^ ((row >> 1) & 3);
    GLDS(Ag + (size_t)row * lda + kt + su * 8, (char*)as_ + (wv * 2 + q) * 1024);
  }
  const int nb = (wv < 2) ? 2 : 1;
  const int bu0 = (wv < 2) ? (2 * wv) : (wv + 2);
  for (int q = 0; q < nb; ++q) {
    int unit = bu0 + q;
    int row = unit * 16 + lr;
    int su = lu ^ ((row >> 1) & 3);
    GLDS(Bg + (size_t)row * rowK + kt + su * 8, (char*)bs_ + unit * 1024);
  }
}

// ------ bf16 MFMA GEMM: 128m x 96n, BK=32, 2-stage / 28KB LDS (5 blk/CU) ---
// occupancy experiment: trade pipeline depth (3->2) for blocks/CU (3->5).
__global__ void __launch_bounds__(256) k_dcgemm(
    const unsigned short* __restrict__ Ap, const unsigned short* __restrict__ Bt,
    unsigned short* __restrict__ Yh, float2* __restrict__ gnp,
    int lda, int rowK, int aOff, int accum, int CperG, int dogn) {
  __shared__ unsigned short As[2][128 * 32];  // 2 x 8 KB
  __shared__ unsigned short Bs[2][96 * 32];   // 2 x 6 KB
  const int tid = threadIdx.x;
  const int lane = tid & 63, wv = tid >> 6;

  const int nwg = gridDim.x;
  const int cpx = nwg >> 3;
  const int bid = blockIdx.x;
  const int l = (bid & 7) * cpx + (bid >> 3);
  const int nm = nwg / 192;
  const int m_i = l % nm;
  const int rest = l / nm;
  const int n_i = rest % 96;
  const int b = rest / 96;

  const int m0 = m_i << 7, n0 = n_i * 96;
  const unsigned short* Ag = Ap + (size_t)m0 * lda + aOff;
  const unsigned short* Bg = Bt + ((size_t)b * HW + n0) * rowK;

  const int wm = (wv >> 1) * 64, wn = (wv & 1) * 48;
  const int fr = lane & 15, hi = lane >> 4;
  const int nt = rowK >> 5;

  f32x4 acc[4][3];
#pragma unroll
  for (int i = 0; i < 4; ++i)
#pragma unroll
    for (int j = 0; j < 3; ++j) acc[i][j] = (f32x4){0.f, 0.f, 0.f, 0.f};

  stage_ab96(Ag, Bg, lda, rowK, 0, &As[0][0], &Bs[0][0], wv, lane);

  for (int t = 0; t < nt; ++t) {
    const int cur = t & 1;
    if (t + 1 < nt) {
      stage_ab96(Ag, Bg, lda, rowK, (t + 1) << 5, &As[cur ^ 1][0], &Bs[cur ^ 1][0],
                 wv, lane);
      // own queue: tile t+1 in flight; drain tile t's loads only
      if (wv < 2) asm volatile("s_waitcnt vmcnt(4)" ::: "memory");
      else        asm volatile("s_waitcnt vmcnt(3)" ::: "memory");
    } else {
      asm volatile("s_waitcnt vmcnt(0)" ::: "memory");
    }
    __builtin_amdgcn_s_barrier();
    __builtin_amdgcn_sched_barrier(0);
    bf16x8 a[4], bb[3];
#pragma unroll
    for (int i = 0; i < 4; ++i) {
      int row = wm + i * 16 + fr;
      a[i] = *(const bf16x8*)&As[cur][row * 32 + ((hi ^ ((row >> 1) & 3)) * 8)];
    }
#pragma unroll
    for (int j = 0; j < 3; ++j) {
      int row = wn + j * 16 + fr;
      bb[j] = *(const bf16x8*)&Bs[cur][row * 32 + ((hi ^ ((row >> 1) & 3)) * 8)];
    }
    __builtin_amdgcn_s_setprio(1);
#pragma unroll
    for (int i = 0; i < 4; ++i)
#pragma unroll
      for (int j = 0; j < 3; ++j)
        acc[i][j] = __builtin_amdgcn_mfma_f32_16x16x32_bf16(a[i], bb[j], acc[i][j], 0, 0, 0);
    __builtin_amdgcn_s_setprio(0);
    __builtin_amdgcn_s_barrier();
  }

  unsigned short* Yb = Yh + (size_t)b * FSTRIDE;
  const int orow = m0 + wm + hi * 4;
  const int ocol = n0 + wn + fr;
  float s_[4], q_[4];
#pragma unroll
  for (int i = 0; i < 4; ++i) { s_[i] = 0.f; q_[i] = 0.f; }
#pragma unroll
  for (int i = 0; i < 4; ++i) {
#pragma unroll
    for (int j = 0; j < 3; ++j) {
      unsigned short* p = Yb + (size_t)(orow + i * 16) * HW + ocol + j * 16;
#pragma unroll
      for (int q = 0; q < 4; ++q) {
        float v = acc[i][j][q];
        if (accum) v += bf2f(p[(size_t)q * HW]);
        p[(size_t)q * HW] = f2bf(v);
        s_[i] += v;
        q_[i] += v * v;
      }
    }
  }

  if (dogn) {
    const int redmax = (CperG == 16) ? 32 : 16;
#pragma unroll
    for (int i = 0; i < 4; ++i) {
      float s = s_[i], q = q_[i];
      for (int off = 1; off <= redmax; off <<= 1) {
        s += __shfl_xor(s, off);
        q += __shfl_xor(q, off);
      }
      int row0 = m0 + wm + i * 16 + ((CperG == 8) ? (lane >> 5) * 8 : 0);
      int g = row0 / CperG;
      bool writer = (CperG == 16) ? (lane == 0) : ((lane & 31) == 0);
      if (writer)
        gnp[(((size_t)(b * 32 + g)) * 96 + n_i) * 2 + (wv & 1)] = make_float2(s, q);
    }
  }
}

// ---------------- GN finalize from dcgemm partials (192 slots/group) -------
__global__ void k_gnfin2(const float2* __restrict__ gnp, float2* __restrict__ stat,
                         int CperG) {
  int t = threadIdx.x;  // 0..63 = b*32+g
  float s = 0.f, q = 0.f;
  for (int j = 0; j < 192; ++j) {
    float2 v = gnp[(size_t)t * 192 + j];
    s += v.x; q += v.y;
  }
  float n = (float)(CperG * HW);
  float m = s / n;
  float var = q / n - m * m;
  stat[t] = make_float2(m, rsqrtf(var + 1e-5f));
}

// ---------------- fallback GN stats from yh (3-chunk path only) ------------
__global__ void __launch_bounds__(256) k_gnstats1h(const unsigned short* __restrict__ yh,
                                                   float2* __restrict__ part, int CperG) {
  const int b = blockIdx.z, g = blockIdx.x, ch = blockIdx.y;
  const int n = CperG * HW;
  const int cs8 = (n >> 4) >> 3;
  const u16x8* p = (const u16x8*)(yh + (size_t)b * FSTRIDE + (size_t)g * n + (size_t)ch * (n >> 4));
  float s = 0.f, q = 0.f;
  for (int i = threadIdx.x; i < cs8; i += 256) {
    u16x8 v = p[i];
#pragma unroll
    for (int j = 0; j < 8; ++j) { float f = bf2f(v[j]); s += f; q += f * f; }
  }
  __shared__ float ss[256], qs[256];
  ss[threadIdx.x] = s; qs[threadIdx.x] = q;
  __syncthreads();
  for (int d = 128; d > 0; d >>= 1) {
    if (threadIdx.x < d) { ss[threadIdx.x] += ss[threadIdx.x + d]; qs[threadIdx.x] += qs[threadIdx.x + d]; }
    __syncthreads();
  }
  if (threadIdx.x == 0) part[((b << 5) + g) * 16 + ch] = make_float2(ss[0], qs[0]);
}

__global__ void k_gnfin(const float2* __restrict__ part, float2* __restrict__ stat,
                        int CperG) {
  int t = threadIdx.x;
  float s = 0.f, q = 0.f;
#pragma unroll
  for (int j = 0; j < 16; ++j) { float2 v = part[t * 16 + j]; s += v.x; q += v.y; }
  float n = (float)(CperG * HW);
  float m = s / n;
  float var = q / n - m * m;
  stat[t] = make_float2(m, rsqrtf(var + 1e-5f));
}

// ------- fused layer-4 GN-apply + cosine partials ----------
__global__ void __launch_bounds__(256) k_gncos(
    const unsigned short* __restrict__ yh, const float2* __restrict__ stat,
    const float* __restrict__ gamma, const float* __restrict__ beta,
    float* __restrict__ res, float4* __restrict__ cospart) {
  int px = blockIdx.x * 256 + threadIdx.x;
  int cc = blockIdx.y;
  float saa = 0.f, sbb = 0.f, sab = 0.f;
  for (int c = cc * 32; c < cc * 32 + 32; ++c) {
    float2 st0 = stat[c >> 3];
    float2 st1 = stat[32 + (c >> 3)];
    float ga = gamma[c], be = beta[c];
    float a = fmaxf((bf2f(yh[(size_t)c * HW + px]) - st0.x) * st0.y * ga + be, 0.f);
    float b = fmaxf((bf2f(yh[(size_t)FSTRIDE + (size_t)c * HW + px]) - st1.x) * st1.y * ga + be, 0.f);
    res[(size_t)c * HW + px] = a;
    res[(size_t)RSTRIDE + (size_t)c * HW + px] = b;
    saa += a * a; sbb += b * b; sab += a * b;
  }
  cospart[(size_t)cc * HW + px] = make_float4(saa, sbb, sab, 0.f);
}

__global__ void k_cos2(const float4* __restrict__ part, float* __restrict__ wpix) {
  int px = blockIdx.x * 256 + threadIdx.x;
  float saa = 0.f, sbb = 0.f, sab = 0.f;
#pragma unroll
  for (int cc = 0; cc < 8; ++cc) {
    float4 v = part[(size_t)cc * HW + px];
    saa += v.x; sbb += v.y; sab += v.z;
  }
  float na = sqrtf(saa), nb = sqrtf(sbb);
  float ttw = saa / fmaxf(na * na, 1e-8f);
  float tkw = sab / fmaxf(na * nb, 1e-8f);
  float m = fmaxf(ttw, tkw);
  float e0 = expf(ttw - m), e1 = expf(tkw - m);
  wpix[px] = e0 / (e0 + e1);
}

__global__ void k_combine(const float* __restrict__ res, const float* __restrict__ wpix,
                          float* __restrict__ out) {
  int i = blockIdx.x * 256 + threadIdx.x;
  int px = i % HW;
  float w0 = wpix[px];
  out[i] = w0 * res[i] + (1.f - w0) * res[(size_t)RSTRIDE + i];
}

extern "C" void kernel_launch(void* const* d_in, const int* in_sizes, int n_in,
                              void* d_out, int out_size, void* d_ws, size_t ws_size,
                              hipStream_t stream) {
  const float* datas = (const float*)d_in[0];
  const float* ow[4] = {(const float*)d_in[1], (const float*)d_in[6],
                        (const float*)d_in[11], (const float*)d_in[16]};
  const float* ob[4] = {(const float*)d_in[2], (const float*)d_in[7],
                        (const float*)d_in[12], (const float*)d_in[17]};
  const float* dw[4] = {(const float*)d_in[3], (const float*)d_in[8],
                        (const float*)d_in[13], (const float*)d_in[18]};
  const float* gg[4] = {(const float*)d_in[4], (const float*)d_in[9],
                        (const float*)d_in[14], (const float*)d_in[19]};
  const float* gb[4] = {(const float*)d_in[5], (const float*)d_in[10],
                        (const float*)d_in[15], (const float*)d_in[20]};

  // full-K layout needs ~247.8 MB (all-layer Ap/Wt hoisted); else 3-chunk.
  const int fullk = (ws_size >= 248500000ull) ? 1 : 0;
  const size_t sampN = fullk ? (2 * (size_t)HW * 4608) : (2 * (size_t)HW * 1536);

  float* ws = (float*)d_ws;
  unsigned short* yh = (unsigned short*)ws;               // 2*FSTRIDE bf16
  float* offp3 = ws + (2 * (size_t)FSTRIDE * 2) / 4;      // 2*3*PXP*32 fp32
  float4* tabw = (float4*)(offp3 + 2 * 3 * (size_t)PXP * 32);
  int4*   tabi = (int4*)(tabw + 2 * (size_t)TABSTRIDE);
  float* wpix = (float*)(tabi + 2 * (size_t)TABSTRIDE);   // HW
  float2* stat = (float2*)(wpix + HW);                    // 64
  float2* gnp  = stat + 64;                               // 2*32*96*2 float2
  float2* gnpart = gnp + 2 * 32 * 96 * 2;                 // 1024 (fallback)
  float4* cospart = (float4*)(gnpart + 1024);             // 8*HW
  float* endp = (float*)(cospart + 8 * (size_t)HW);
  size_t ofs = ((size_t)(endp - ws) + 3) & ~(size_t)3;
  unsigned short* samp = (unsigned short*)(ws + ofs);
  unsigned short* apAll = samp + sampN;                   // 7667712 us
  unsigned short* wtAll = apAll + (size_t)7667712;        // 589824 us
  unsigned short* ftp512 = wtAll + (size_t)589824;        // 2*FTPROWS*512
  unsigned short* ftp256 = fullk ? (samp + 2 * (size_t)HW * 2304)
                                 : (ftp512 + 2 * (size_t)FTPROWS * 512);
  float* res = (float*)(ftp256 + 2 * (size_t)FTPROWS * 256);

  dim3 blk(256);
  k_zero<<<dim3(2 * FTPROWS * 512 / 8 / 256), blk, 0, stream>>>(ftp512, 2u * FTPROWS * 512 / 8);
  k_prepA_all<<<dim3(29952), blk, 0, stream>>>(dw[0], dw[1], dw[2], dw[3], apAll);
  k_prepW_all<<<dim3(2304), blk, 0, stream>>>(ow[0], ow[1], ow[2], ow[3], wtAll);

  for (int lyr = 0; lyr < 4; ++lyr) {
    const int Cx = (lyr < 3) ? 512 : 256;
    const int M  = Cx;
    const int CperG = (lyr < 3) ? 16 : 8;
    const unsigned short* Ap = (lyr < 3) ? (apAll + (size_t)lyr * 2359296)
                                         : (apAll + (size_t)7077888);
    const unsigned short* Wt = wtAll + (size_t)lyr * 147456;
    if (lyr == 0) {
      k_mkftp_cat<<<dim3(144, 8, 2), blk, 0, stream>>>(datas + RSTRIDE, datas,
                                                       datas + RSTRIDE, ftp512, 512, 256);
    } else {
      k_mkftp_gn<<<dim3(144, 8, 2), blk, 0, stream>>>(yh, stat, gg[lyr - 1], gb[lyr - 1],
                                                      ftp512);
    }
    k_offmm<<<dim3(576), blk, 0, stream>>>(ftp512, Wt, offp3);
    k_table<<<dim3(36, 9, 2), blk, 0, stream>>>(offp3, ob[lyr], tabi, tabw);
    const unsigned short* sftp;
    if (lyr < 3) {
      sftp = ftp512;
    } else {
      k_zero<<<dim3(2 * FTPROWS * 256 / 8 / 256), blk, 0, stream>>>(ftp256, 2u * FTPROWS * 256 / 8);
      k_mkftp_cat<<<dim3(144, 4, 2), blk, 0, stream>>>(datas + RSTRIDE, datas,
                                                       datas, ftp256, 256, 256);
      sftp = ftp256;
    }
    const int nch = fullk ? 1 : 3;
    const int nk = 9 / nch;
    const int rowK = nk * Cx;
    const int yc = Cx / 64;
    for (int ch = 0; ch < nch; ++ch) {
      k_sample_t<<<dim3(144 * yc * 2 * nk), blk, 0, stream>>>(sftp, tabi, tabw, samp,
                                                              Cx, ch * nk, rowK, yc);
      k_dcgemm<<<dim3((M / 128) * 96 * 2), blk, 0, stream>>>(
          Ap, samp, yh, gnp, 9 * Cx, rowK, ch * rowK, ch > 0, CperG,
          fullk && (ch == nch - 1));
    }
    if (fullk) {
      k_gnfin2<<<dim3(1), dim3(64), 0, stream>>>(gnp, stat, CperG);
    } else {
      k_gnstats1h<<<dim3(32, 16, 2), blk, 0, stream>>>(yh, gnpart, CperG);
      k_gnfin<<<dim3(1), dim3(64), 0, stream>>>(gnpart, stat, CperG);
    }
  }

  // layer-4 fused GN-apply + cosine partials, then blend
  k_gncos<<<dim3(36, 8), blk, 0, stream>>>(yh, stat, gg[3], gb[3], res, cospart);
  k_cos2<<<dim3(36), blk, 0, stream>>>(cospart, wpix);
  k_combine<<<dim3(RSTRIDE / 256), blk, 0, stream>>>(res, wpix, (float*)d_out);
}